// Round 9
// baseline (983.772 us; speedup 1.0000x reference)
//
#include <hip/hip_runtime.h>
#include <math.h>

#define NN 50000
#define NE 1200000
#define FIN 128
#define FE 32
#define H 78
#define HP 80
#define ETOT (NE + NN)
#define NG (HP / 4)          // 20 float4 groups per node row

#define NPB 64                                   // nodes per bucket
#define NBUCK ((NN + NPB - 1) / NPB)             // 782
#define BCAP 2560                                // max edges/bucket in LDS (mean ~1600)

typedef __attribute__((ext_vector_type(8))) short bf16x8;
typedef __attribute__((ext_vector_type(4))) float f32x4;

__device__ __forceinline__ unsigned short f2bf(float f) {   // RNE float->bf16
  unsigned u = __float_as_uint(f);
  return (unsigned short)((u + 0x7FFFu + ((u >> 16) & 1u)) >> 16);
}

// ---------------- dense node GEMM with fused attention-score epilogue ----------------
template<int K, int LDA>
__global__ void gemm_node(const float* __restrict__ A, const float* __restrict__ W,
                          const float* __restrict__ as, const float* __restrict__ ad,
                          float* __restrict__ C, float* __restrict__ asv,
                          float* __restrict__ adv) {
  int n = blockIdx.x * blockDim.x + threadIdx.x;
  if (n >= NN) return;
  const float* a = A + (size_t)n * LDA;
  float acc[H];
#pragma unroll
  for (int j = 0; j < H; ++j) acc[j] = 0.f;
  int k = 0;
  for (; k + 4 <= K; k += 4) {
    float4 av = *reinterpret_cast<const float4*>(a + k);
    const float* w0 = W + (size_t)k * H;
#pragma unroll
    for (int j = 0; j < H; ++j) acc[j] += av.x * w0[j];
#pragma unroll
    for (int j = 0; j < H; ++j) acc[j] += av.y * w0[H + j];
#pragma unroll
    for (int j = 0; j < H; ++j) acc[j] += av.z * w0[2 * H + j];
#pragma unroll
    for (int j = 0; j < H; ++j) acc[j] += av.w * w0[3 * H + j];
  }
  for (; k < K; ++k) {
    float av = a[k];
    const float* w0 = W + (size_t)k * H;
#pragma unroll
    for (int j = 0; j < H; ++j) acc[j] += av * w0[j];
  }
  float* c = C + (size_t)n * HP;
#pragma unroll
  for (int j = 0; j < H; ++j) c[j] = acc[j];
  c[H] = 0.f;
  c[H + 1] = 0.f;
  float sa = 0.f, sd = 0.f;
#pragma unroll
  for (int j = 0; j < H; ++j) {
    sa += acc[j] * as[j];
    sd += acc[j] * ad[j];
  }
  asv[n] = sa;
  adv[n] = sd;
}

// ---------------- bucketed CSR build (dst-sorted) ----------------
__global__ void zero_buckets(int* __restrict__ bcount) {
  int t = threadIdx.x;
  if (t < NBUCK) bcount[t] = 0;
}

__global__ void bucket_count(const int* __restrict__ ei, int* __restrict__ bcount) {
  int i = blockIdx.x * blockDim.x + threadIdx.x;
  if (i >= ETOT) return;
  int dst = (i < NE) ? ei[NE + i] : (i - NE);
  atomicAdd(bcount + (dst >> 6), 1);    // NPB = 64
}

__global__ void scan_buckets(const int* __restrict__ bcount, int* __restrict__ bstart,
                             int* __restrict__ bcursor, int* __restrict__ rowptr) {
  __shared__ int sh[1024];
  int t = threadIdx.x;
  sh[t] = (t < NBUCK) ? bcount[t] : 0;
  __syncthreads();
  for (int off = 1; off < 1024; off <<= 1) {
    int v = (t >= off) ? sh[t - off] : 0;
    __syncthreads();
    sh[t] += v;
    __syncthreads();
  }
  if (t < NBUCK) {
    int ex = (t == 0) ? 0 : sh[t - 1];
    bstart[t] = ex;
    bcursor[t] = ex;
  }
  if (t == 0) rowptr[NN] = ETOT;
}

// append (src,dst) into the dst's bucket region; positions allocated in time
// order -> 782 concurrent sequential append streams -> coalesced line writes
__global__ void bucket_place(const int* __restrict__ ei, int* __restrict__ bcursor,
                             unsigned long long* __restrict__ tmp) {
  int i = blockIdx.x * blockDim.x + threadIdx.x;
  if (i >= ETOT) return;
  int src, dst;
  if (i < NE) { src = ei[i]; dst = ei[NE + i]; }
  else { src = dst = i - NE; }
  int pos = atomicAdd(bcursor + (dst >> 6), 1);
  tmp[pos] = ((unsigned long long)(unsigned)dst << 32) | (unsigned)src;
}

// per-bucket: LDS histogram -> local rowptr -> LDS scatter -> coalesced write
__global__ __launch_bounds__(256)
void bucket_build(const unsigned long long* __restrict__ tmp,
                  const int* __restrict__ bstart, const int* __restrict__ bcount,
                  int* __restrict__ rowptr, int* __restrict__ srcs) {
  __shared__ int hist[NPB];
  __shared__ int offs[NPB];
  __shared__ int curs[NPB];
  __shared__ int srcs_l[BCAP];
  int b = blockIdx.x, t = threadIdx.x;
  int base = bstart[b];
  int cnt = bcount[b];
  int n0 = b * NPB;
  if (t < NPB) hist[t] = 0;
  __syncthreads();
  for (int p = t; p < cnt; p += 256) {
    int dst = (int)(tmp[base + p] >> 32);
    atomicAdd(&hist[dst - n0], 1);
  }
  __syncthreads();
  if (t == 0) {
    int run = 0;
    for (int j = 0; j < NPB; ++j) { offs[j] = run; run += hist[j]; }
  }
  __syncthreads();
  if (t < NPB) {
    curs[t] = offs[t];
    int n = n0 + t;
    if (n < NN) rowptr[n] = base + offs[t];
  }
  __syncthreads();
  for (int p = t; p < cnt; p += 256) {
    unsigned long long e = tmp[base + p];
    int dst = (int)(e >> 32);
    int src = (int)(e & 0xffffffffULL);
    int lp = atomicAdd(&curs[dst - n0], 1);
    if (lp < BCAP) srcs_l[lp] = src;
    else srcs[base + lp] = src;       // overflow fallback (statistically never)
  }
  __syncthreads();
  int m = cnt < BCAP ? cnt : BCAP;
  for (int p = t; p < m; p += 256) srcs[base + p] = srcs_l[p];
}

// ---------------- per-destination ONLINE softmax (1 random-gather pass) ----------------
__global__ void softmax_csr(const int* __restrict__ rowptr, const int* __restrict__ srcs,
                            const float* __restrict__ asv, const float* __restrict__ adv,
                            float* __restrict__ aw) {
  int n = blockIdx.x * blockDim.x + threadIdx.x;
  if (n >= NN) return;
  int r0 = rowptr[n], r1 = rowptr[n + 1];
  float advn = adv[n];
  float m = -INFINITY, s = 0.f;
  for (int p = r0; p < r1; ++p) {
    float e = asv[srcs[p]] + advn;
    e = e > 0.f ? e : 0.2f * e;
    aw[p] = e;
    if (e > m) {
      s = s * __expf(m - e);   // exp(-inf)=0 handles first iteration
      m = e;
    }
    s += __expf(e - m);
  }
  float inv = 1.f / (s + 1e-16f);
  for (int p = r0; p < r1; ++p) aw[p] = __expf(aw[p] - m) * inv;
}

// ---------------- gather-based aggregation; bias (+optional relu) fused ----------------
template<int RELU>
__global__ void agg_csr(const int* __restrict__ rowptr, const int* __restrict__ srcs,
                        const float* __restrict__ aw, const float* __restrict__ h,
                        const float* __restrict__ biasp, float* __restrict__ outp) {
  int t = blockIdx.x * blockDim.x + threadIdx.x;
  if (t >= NN * NG) return;
  int n = t / NG;
  int g = t - n * NG;
  int r0 = rowptr[n], r1 = rowptr[n + 1];
  float ax = 0.f, ay = 0.f, az = 0.f, aww = 0.f;
  const float* hb = h + (size_t)g * 4;
  for (int p = r0; p < r1; ++p) {
    float al = aw[p];
    int s = srcs[p];
    float4 hv = *reinterpret_cast<const float4*>(hb + (size_t)s * HP);
    ax += al * hv.x;
    ay += al * hv.y;
    az += al * hv.z;
    aww += al * hv.w;
  }
  float4 bv = *reinterpret_cast<const float4*>(biasp + g * 4);
  float4 r;
  r.x = ax + bv.x; r.y = ay + bv.y; r.z = az + bv.z; r.w = aww + bv.w;
  if (RELU) {
    r.x = fmaxf(r.x, 0.f); r.y = fmaxf(r.y, 0.f);
    r.z = fmaxf(r.z, 0.f); r.w = fmaxf(r.w, 0.f);
  }
  *reinterpret_cast<float4*>(outp + (size_t)n * HP + g * 4) = r;
}

__global__ void prep_bias(const float* __restrict__ b1, const float* __restrict__ b2,
                          float* __restrict__ b1p, float* __restrict__ b2p) {
  int t = threadIdx.x;
  if (t < HP) {
    b1p[t] = (t < H) ? b1[t] : 0.f;
    b2p[t] = (t < H) ? b2[t] : 0.f;
  }
}

__global__ void final_node(const float* __restrict__ h2f, const float* __restrict__ Wf,
                           float* __restrict__ u, float* __restrict__ v) {
  int n = blockIdx.x * blockDim.x + threadIdx.x;
  if (n >= NN) return;
  const float* r = h2f + (size_t)n * HP;
  float su = 0.f, sv = 0.f;
#pragma unroll
  for (int j = 0; j < H; ++j) {
    float hv = r[j];
    su += hv * Wf[j];
    sv += hv * Wf[H + j];
  }
  u[n] = su;
  v[n] = sv;
}

__global__ void mk_wproj(const float* __restrict__ Wm2, const float* __restrict__ bm2,
                         const float* __restrict__ Wf, const float* __restrict__ bf,
                         float* __restrict__ wpc) {
  int k = threadIdx.x;
  if (k < H) {
    float s = 0.f;
    for (int j = 0; j < H; ++j) s += Wm2[k * H + j] * Wf[2 * H + j];
    wpc[k] = s;
  } else if (k == H) {
    float s = 0.f;
    for (int j = 0; j < H; ++j) s += bm2[j] * Wf[2 * H + j];
    wpc[H] = s + bf[0];
  }
}

// ---------------- edge head via MFMA: ea[E x 32] @ Wm1[32 x 78] -------------
#define FE_WAVES 18750          // NE / 64 edges per wave
__global__ __launch_bounds__(256)
void final_edge_mfma(const int* __restrict__ ei, const float* __restrict__ ea,
                     const float* __restrict__ Wm1, const float* __restrict__ bm1,
                     const float* __restrict__ wpc, const float* __restrict__ u,
                     const float* __restrict__ v, float* __restrict__ out) {
  int lane = threadIdx.x & 63;
  long gw = (long)blockIdx.x * 4 + (threadIdx.x >> 6);
  if (gw >= FE_WAVES) return;
  int l15 = lane & 15;
  int kg = lane >> 4;                    // k-group 0..3
  bf16x8 bfrag[5];
  float bm1c[5], wpcc[5];
#pragma unroll
  for (int g = 0; g < 5; ++g) {
    int col = g * 16 + l15;
    bool valid = col < H;
    bm1c[g] = valid ? bm1[col] : 0.f;
    wpcc[g] = valid ? wpc[col] : 0.f;
#pragma unroll
    for (int e = 0; e < 8; ++e) {
      int kk = kg * 8 + e;
      bfrag[g][e] = valid ? (short)f2bf(Wm1[kk * H + col]) : (short)0;
    }
  }
  float basec = wpc[H];
  int e0 = (int)(gw * 64);
#pragma unroll
  for (int t = 0; t < 4; ++t) {
    int ebase = e0 + t * 16;
    const float* ar = ea + (size_t)(ebase + l15) * FE + kg * 8;
    float4 f0 = *reinterpret_cast<const float4*>(ar);
    float4 f1 = *reinterpret_cast<const float4*>(ar + 4);
    bf16x8 afrag;
    afrag[0] = (short)f2bf(f0.x); afrag[1] = (short)f2bf(f0.y);
    afrag[2] = (short)f2bf(f0.z); afrag[3] = (short)f2bf(f0.w);
    afrag[4] = (short)f2bf(f1.x); afrag[5] = (short)f2bf(f1.y);
    afrag[6] = (short)f2bf(f1.z); afrag[7] = (short)f2bf(f1.w);
    float es0 = 0.f, es1 = 0.f, es2 = 0.f, es3 = 0.f;
#pragma unroll
    for (int g = 0; g < 5; ++g) {
      f32x4 c = {0.f, 0.f, 0.f, 0.f};
      c = __builtin_amdgcn_mfma_f32_16x16x32_bf16(afrag, bfrag[g], c, 0, 0, 0);
      es0 = fmaf(fmaxf(c[0] + bm1c[g], 0.f), wpcc[g], es0);
      es1 = fmaf(fmaxf(c[1] + bm1c[g], 0.f), wpcc[g], es1);
      es2 = fmaf(fmaxf(c[2] + bm1c[g], 0.f), wpcc[g], es2);
      es3 = fmaf(fmaxf(c[3] + bm1c[g], 0.f), wpcc[g], es3);
    }
#pragma unroll
    for (int m = 1; m < 16; m <<= 1) {
      es0 += __shfl_xor(es0, m);
      es1 += __shfl_xor(es1, m);
      es2 += __shfl_xor(es2, m);
      es3 += __shfl_xor(es3, m);
    }
    if (l15 < 4) {
      float es = (l15 == 0) ? es0 : (l15 == 1) ? es1 : (l15 == 2) ? es2 : es3;
      int e = ebase + kg * 4 + l15;
      int s = ei[e], d = ei[NE + e];
      out[e] = es + u[s] + v[d] + basec;
    }
  }
}

extern "C" void kernel_launch(void* const* d_in, const int* in_sizes, int n_in,
                              void* d_out, int out_size, void* d_ws, size_t ws_size,
                              hipStream_t stream) {
  const float* x   = (const float*)d_in[0];
  const int*   ei  = (const int*)d_in[1];
  const float* ea  = (const float*)d_in[2];
  const float* W1  = (const float*)d_in[3];
  const float* as1 = (const float*)d_in[4];
  const float* ad1 = (const float*)d_in[5];
  const float* b1  = (const float*)d_in[6];
  const float* W2  = (const float*)d_in[7];
  const float* as2 = (const float*)d_in[8];
  const float* ad2 = (const float*)d_in[9];
  const float* b2  = (const float*)d_in[10];
  const float* Wm1 = (const float*)d_in[11];
  const float* bm1 = (const float*)d_in[12];
  const float* Wm2 = (const float*)d_in[13];
  const float* bm2 = (const float*)d_in[14];
  const float* Wf  = (const float*)d_in[15];
  const float* bf  = (const float*)d_in[16];
  float* out = (float*)d_out;

  float* w = (float*)d_ws;
  float* h1   = w; w += (size_t)NN * HP;   // layer1 h; later reused as layer2 agg out
  float* bufB = w; w += (size_t)NN * HP;   // layer1 agg out (h1r) = layer2 gemm input
  float* h2   = w; w += (size_t)NN * HP;
  float* asv  = w; w += NN;
  float* adv  = w; w += NN;
  float* uu   = w; w += NN;
  float* vv   = w; w += NN;
  float* wpc  = w; w += HP;
  float* b1p  = w; w += HP;
  float* b2p  = w; w += HP;
  float* aw   = w; w += ETOT;
  unsigned long long* tmp = (unsigned long long*)w; w += 2 * (size_t)ETOT;  // 8B each
  int* rowptr = (int*)w; w += NN + 1;
  int* srcs   = (int*)w; w += ETOT;
  int* bcount = (int*)w; w += NBUCK;
  int* bstart = (int*)w; w += NBUCK;
  int* bcursor= (int*)w; w += NBUCK;

  const int B = 256;
  dim3 gN((NN + B - 1) / B);
  dim3 gE((ETOT + B - 1) / B);
  dim3 gA((NN * NG + B - 1) / B);
  dim3 gFE((FE_WAVES + 3) / 4);

  // ---- bucketed CSR build (dst-sorted) ----
  zero_buckets<<<1, 1024, 0, stream>>>(bcount);
  bucket_count<<<gE, B, 0, stream>>>(ei, bcount);
  scan_buckets<<<1, 1024, 0, stream>>>(bcount, bstart, bcursor, rowptr);
  bucket_place<<<gE, B, 0, stream>>>(ei, bcursor, tmp);
  bucket_build<<<NBUCK, 256, 0, stream>>>(tmp, bstart, bcount, rowptr, srcs);
  prep_bias<<<1, 128, 0, stream>>>(b1, b2, b1p, b2p);

  // ---- layer 1 ----
  gemm_node<FIN, FIN><<<gN, B, 0, stream>>>(x, W1, as1, ad1, h1, asv, adv);
  softmax_csr<<<gN, B, 0, stream>>>(rowptr, srcs, asv, adv, aw);
  agg_csr<1><<<gA, B, 0, stream>>>(rowptr, srcs, aw, h1, b1p, bufB);

  // ---- layer 2 ----
  gemm_node<H, HP><<<gN, B, 0, stream>>>(bufB, W2, as2, ad2, h2, asv, adv);
  softmax_csr<<<gN, B, 0, stream>>>(rowptr, srcs, asv, adv, aw);
  agg_csr<0><<<gA, B, 0, stream>>>(rowptr, srcs, aw, h2, b2p, h1);
  final_node<<<gN, B, 0, stream>>>(h1, Wf, uu, vv);

  // ---- edge head ----
  mk_wproj<<<1, 128, 0, stream>>>(Wm2, bm2, Wf, bf, wpc);
  final_edge_mfma<<<gFE, B, 0, stream>>>(ei, ea, Wm1, bm1, wpc, uu, vv, out);
}

// Round 10
// 405.463 us; speedup vs baseline: 2.4263x; 2.4263x over previous
//
#include <hip/hip_runtime.h>
#include <math.h>

#define NN 50000
#define NE 1200000
#define FIN 128
#define FE 32
#define H 78
#define HP 80
#define ETOT (NE + NN)
#define NG (HP / 4)          // 20 float4 groups per node row

#define NPB 64                                   // nodes per bucket
#define NBUCK ((NN + NPB - 1) / NPB)             // 782
#define BCAP 2560                                // max edges/bucket in LDS (mean ~1600)

#define EB 6400                                  // edges per binning block
#define NBE ((ETOT + EB - 1) / EB)               // 196 binning blocks
#define GHN (NBUCK * NBE)                        // 153272 histogram cells
#define GS_NB ((GHN + 1023) / 1024)              // 150 scan tiles

typedef __attribute__((ext_vector_type(8))) short bf16x8;
typedef __attribute__((ext_vector_type(4))) float f32x4;

__device__ __forceinline__ unsigned short f2bf(float f) {   // RNE float->bf16
  unsigned u = __float_as_uint(f);
  return (unsigned short)((u + 0x7FFFu + ((u >> 16) & 1u)) >> 16);
}

// ---------------- dense node GEMM with fused attention-score epilogue ----------------
template<int K, int LDA>
__global__ void gemm_node(const float* __restrict__ A, const float* __restrict__ W,
                          const float* __restrict__ as, const float* __restrict__ ad,
                          float* __restrict__ C, float* __restrict__ asv,
                          float* __restrict__ adv) {
  int n = blockIdx.x * blockDim.x + threadIdx.x;
  if (n >= NN) return;
  const float* a = A + (size_t)n * LDA;
  float acc[H];
#pragma unroll
  for (int j = 0; j < H; ++j) acc[j] = 0.f;
  int k = 0;
  for (; k + 4 <= K; k += 4) {
    float4 av = *reinterpret_cast<const float4*>(a + k);
    const float* w0 = W + (size_t)k * H;
#pragma unroll
    for (int j = 0; j < H; ++j) acc[j] += av.x * w0[j];
#pragma unroll
    for (int j = 0; j < H; ++j) acc[j] += av.y * w0[H + j];
#pragma unroll
    for (int j = 0; j < H; ++j) acc[j] += av.z * w0[2 * H + j];
#pragma unroll
    for (int j = 0; j < H; ++j) acc[j] += av.w * w0[3 * H + j];
  }
  for (; k < K; ++k) {
    float av = a[k];
    const float* w0 = W + (size_t)k * H;
#pragma unroll
    for (int j = 0; j < H; ++j) acc[j] += av * w0[j];
  }
  float* c = C + (size_t)n * HP;
#pragma unroll
  for (int j = 0; j < H; ++j) c[j] = acc[j];
  c[H] = 0.f;
  c[H + 1] = 0.f;
  float sa = 0.f, sd = 0.f;
#pragma unroll
  for (int j = 0; j < H; ++j) {
    sa += acc[j] * as[j];
    sd += acc[j] * ad[j];
  }
  asv[n] = sa;
  adv[n] = sd;
}

// ---------------- CSR build: blocked counting sort, no global atomics --------------
// phase 1: per-block LDS histogram of dst-buckets -> gh[bucket][block]
__global__ __launch_bounds__(256)
void bin_hist(const int* __restrict__ ei, int* __restrict__ gh) {
  __shared__ int hist[NBUCK];
  int b = blockIdx.x, t = threadIdx.x;
  for (int k = t; k < NBUCK; k += 256) hist[k] = 0;
  __syncthreads();
  int e0 = b * EB;
  int e1 = min(e0 + EB, ETOT);
  for (int i = e0 + t; i < e1; i += 256) {
    int dst = (i < NE) ? ei[NE + i] : (i - NE);
    atomicAdd(&hist[dst >> 6], 1);
  }
  __syncthreads();
  for (int k = t; k < NBUCK; k += 256) gh[(size_t)k * NBE + b] = hist[k];
}

// 3-phase exclusive scan over gh[0..GHN)
__global__ void scan1g(const int* __restrict__ gh, int* __restrict__ gsum) {
  __shared__ int sh[256];
  int b = blockIdx.x, t = threadIdx.x;
  int i0 = b * 1024 + t * 4;
  int s = 0;
#pragma unroll
  for (int k = 0; k < 4; ++k) {
    int i = i0 + k;
    if (i < GHN) s += gh[i];
  }
  sh[t] = s;
  __syncthreads();
  for (int off = 128; off > 0; off >>= 1) {
    if (t < off) sh[t] += sh[t + off];
    __syncthreads();
  }
  if (t == 0) gsum[b] = sh[0];
}

__global__ void scan2g(const int* __restrict__ gsum, int* __restrict__ gboff) {
  __shared__ int sh[256];
  int t = threadIdx.x;
  sh[t] = (t < GS_NB) ? gsum[t] : 0;
  __syncthreads();
  for (int off = 1; off < 256; off <<= 1) {
    int v = (t >= off) ? sh[t - off] : 0;
    __syncthreads();
    sh[t] += v;
    __syncthreads();
  }
  if (t < GS_NB) gboff[t] = (t == 0) ? 0 : sh[t - 1];
}

__global__ void scan3g(const int* __restrict__ gh, const int* __restrict__ gboff,
                       int* __restrict__ goff) {
  __shared__ int sh[256];
  int b = blockIdx.x, t = threadIdx.x;
  int i0 = b * 1024 + t * 4;
  int v[4];
  int s = 0;
#pragma unroll
  for (int k = 0; k < 4; ++k) {
    int i = i0 + k;
    v[k] = (i < GHN) ? gh[i] : 0;
    s += v[k];
  }
  sh[t] = s;
  __syncthreads();
  for (int off = 1; off < 256; off <<= 1) {
    int u = (t >= off) ? sh[t - off] : 0;
    __syncthreads();
    sh[t] += u;
    __syncthreads();
  }
  int run = gboff[b] + ((t == 0) ? 0 : sh[t - 1]);
#pragma unroll
  for (int k = 0; k < 4; ++k) {
    int i = i0 + k;
    if (i < GHN) { goff[i] = run; run += v[k]; }
  }
}

// phase 3: re-read edges, rank via LDS cursors (no global atomics), write runs
__global__ __launch_bounds__(256)
void bin_place(const int* __restrict__ ei, const int* __restrict__ goff,
               unsigned long long* __restrict__ tmp) {
  __shared__ int cursor[NBUCK];
  int b = blockIdx.x, t = threadIdx.x;
  for (int k = t; k < NBUCK; k += 256) cursor[k] = goff[(size_t)k * NBE + b];
  __syncthreads();
  int e0 = b * EB;
  int e1 = min(e0 + EB, ETOT);
  for (int i = e0 + t; i < e1; i += 256) {
    int src, dst;
    if (i < NE) { src = ei[i]; dst = ei[NE + i]; }
    else { src = dst = i - NE; }
    int pos = atomicAdd(&cursor[dst >> 6], 1);
    tmp[pos] = ((unsigned long long)(unsigned)dst << 32) | (unsigned)src;
  }
}

// per-bucket: LDS histogram -> local rowptr -> LDS scatter -> coalesced write
__global__ __launch_bounds__(256)
void bucket_build(const unsigned long long* __restrict__ tmp,
                  const int* __restrict__ goff,
                  int* __restrict__ rowptr, int* __restrict__ srcs) {
  __shared__ int hist[NPB];
  __shared__ int offs[NPB];
  __shared__ int curs[NPB];
  __shared__ int srcs_l[BCAP];
  int b = blockIdx.x, t = threadIdx.x;
  int base = goff[(size_t)b * NBE];
  int next = (b + 1 < NBUCK) ? goff[(size_t)(b + 1) * NBE] : ETOT;
  int cnt = next - base;
  int n0 = b * NPB;
  if (t < NPB) hist[t] = 0;
  __syncthreads();
  for (int p = t; p < cnt; p += 256) {
    int dst = (int)(tmp[base + p] >> 32);
    atomicAdd(&hist[dst - n0], 1);
  }
  __syncthreads();
  if (t == 0) {
    int run = 0;
    for (int j = 0; j < NPB; ++j) { offs[j] = run; run += hist[j]; }
  }
  __syncthreads();
  if (t < NPB) {
    curs[t] = offs[t];
    int n = n0 + t;
    if (n < NN) rowptr[n] = base + offs[t];
  }
  if (b == NBUCK - 1 && t == 0) rowptr[NN] = ETOT;
  __syncthreads();
  for (int p = t; p < cnt; p += 256) {
    unsigned long long e = tmp[base + p];
    int dst = (int)(e >> 32);
    int src = (int)(e & 0xffffffffULL);
    int lp = atomicAdd(&curs[dst - n0], 1);
    if (lp < BCAP) srcs_l[lp] = src;
    else srcs[base + lp] = src;       // overflow fallback (statistically never)
  }
  __syncthreads();
  int m = cnt < BCAP ? cnt : BCAP;
  for (int p = t; p < m; p += 256) srcs[base + p] = srcs_l[p];
}

// ---------------- per-destination ONLINE softmax (1 random-gather pass) ----------------
__global__ void softmax_csr(const int* __restrict__ rowptr, const int* __restrict__ srcs,
                            const float* __restrict__ asv, const float* __restrict__ adv,
                            float* __restrict__ aw) {
  int n = blockIdx.x * blockDim.x + threadIdx.x;
  if (n >= NN) return;
  int r0 = rowptr[n], r1 = rowptr[n + 1];
  float advn = adv[n];
  float m = -INFINITY, s = 0.f;
  for (int p = r0; p < r1; ++p) {
    float e = asv[srcs[p]] + advn;
    e = e > 0.f ? e : 0.2f * e;
    aw[p] = e;
    if (e > m) {
      s = s * __expf(m - e);   // exp(-inf)=0 handles first iteration
      m = e;
    }
    s += __expf(e - m);
  }
  float inv = 1.f / (s + 1e-16f);
  for (int p = r0; p < r1; ++p) aw[p] = __expf(aw[p] - m) * inv;
}

// ---------------- gather-based aggregation; bias (+optional relu) fused ----------------
template<int RELU>
__global__ void agg_csr(const int* __restrict__ rowptr, const int* __restrict__ srcs,
                        const float* __restrict__ aw, const float* __restrict__ h,
                        const float* __restrict__ biasp, float* __restrict__ outp) {
  int t = blockIdx.x * blockDim.x + threadIdx.x;
  if (t >= NN * NG) return;
  int n = t / NG;
  int g = t - n * NG;
  int r0 = rowptr[n], r1 = rowptr[n + 1];
  float ax = 0.f, ay = 0.f, az = 0.f, aww = 0.f;
  const float* hb = h + (size_t)g * 4;
  for (int p = r0; p < r1; ++p) {
    float al = aw[p];
    int s = srcs[p];
    float4 hv = *reinterpret_cast<const float4*>(hb + (size_t)s * HP);
    ax += al * hv.x;
    ay += al * hv.y;
    az += al * hv.z;
    aww += al * hv.w;
  }
  float4 bv = *reinterpret_cast<const float4*>(biasp + g * 4);
  float4 r;
  r.x = ax + bv.x; r.y = ay + bv.y; r.z = az + bv.z; r.w = aww + bv.w;
  if (RELU) {
    r.x = fmaxf(r.x, 0.f); r.y = fmaxf(r.y, 0.f);
    r.z = fmaxf(r.z, 0.f); r.w = fmaxf(r.w, 0.f);
  }
  *reinterpret_cast<float4*>(outp + (size_t)n * HP + g * 4) = r;
}

__global__ void prep_bias(const float* __restrict__ b1, const float* __restrict__ b2,
                          float* __restrict__ b1p, float* __restrict__ b2p) {
  int t = threadIdx.x;
  if (t < HP) {
    b1p[t] = (t < H) ? b1[t] : 0.f;
    b2p[t] = (t < H) ? b2[t] : 0.f;
  }
}

__global__ void final_node(const float* __restrict__ h2f, const float* __restrict__ Wf,
                           float* __restrict__ u, float* __restrict__ v) {
  int n = blockIdx.x * blockDim.x + threadIdx.x;
  if (n >= NN) return;
  const float* r = h2f + (size_t)n * HP;
  float su = 0.f, sv = 0.f;
#pragma unroll
  for (int j = 0; j < H; ++j) {
    float hv = r[j];
    su += hv * Wf[j];
    sv += hv * Wf[H + j];
  }
  u[n] = su;
  v[n] = sv;
}

__global__ void mk_wproj(const float* __restrict__ Wm2, const float* __restrict__ bm2,
                         const float* __restrict__ Wf, const float* __restrict__ bf,
                         float* __restrict__ wpc) {
  int k = threadIdx.x;
  if (k < H) {
    float s = 0.f;
    for (int j = 0; j < H; ++j) s += Wm2[k * H + j] * Wf[2 * H + j];
    wpc[k] = s;
  } else if (k == H) {
    float s = 0.f;
    for (int j = 0; j < H; ++j) s += bm2[j] * Wf[2 * H + j];
    wpc[H] = s + bf[0];
  }
}

// ---------------- edge head via MFMA: ea[E x 32] @ Wm1[32 x 78] -------------
#define FE_WAVES 18750          // NE / 64 edges per wave
__global__ __launch_bounds__(256)
void final_edge_mfma(const int* __restrict__ ei, const float* __restrict__ ea,
                     const float* __restrict__ Wm1, const float* __restrict__ bm1,
                     const float* __restrict__ wpc, const float* __restrict__ u,
                     const float* __restrict__ v, float* __restrict__ out) {
  int lane = threadIdx.x & 63;
  long gw = (long)blockIdx.x * 4 + (threadIdx.x >> 6);
  if (gw >= FE_WAVES) return;
  int l15 = lane & 15;
  int kg = lane >> 4;                    // k-group 0..3
  bf16x8 bfrag[5];
  float bm1c[5], wpcc[5];
#pragma unroll
  for (int g = 0; g < 5; ++g) {
    int col = g * 16 + l15;
    bool valid = col < H;
    bm1c[g] = valid ? bm1[col] : 0.f;
    wpcc[g] = valid ? wpc[col] : 0.f;
#pragma unroll
    for (int e = 0; e < 8; ++e) {
      int kk = kg * 8 + e;
      bfrag[g][e] = valid ? (short)f2bf(Wm1[kk * H + col]) : (short)0;
    }
  }
  float basec = wpc[H];
  int e0 = (int)(gw * 64);
#pragma unroll
  for (int t = 0; t < 4; ++t) {
    int ebase = e0 + t * 16;
    const float* ar = ea + (size_t)(ebase + l15) * FE + kg * 8;
    float4 f0 = *reinterpret_cast<const float4*>(ar);
    float4 f1 = *reinterpret_cast<const float4*>(ar + 4);
    bf16x8 afrag;
    afrag[0] = (short)f2bf(f0.x); afrag[1] = (short)f2bf(f0.y);
    afrag[2] = (short)f2bf(f0.z); afrag[3] = (short)f2bf(f0.w);
    afrag[4] = (short)f2bf(f1.x); afrag[5] = (short)f2bf(f1.y);
    afrag[6] = (short)f2bf(f1.z); afrag[7] = (short)f2bf(f1.w);
    float es0 = 0.f, es1 = 0.f, es2 = 0.f, es3 = 0.f;
#pragma unroll
    for (int g = 0; g < 5; ++g) {
      f32x4 c = {0.f, 0.f, 0.f, 0.f};
      c = __builtin_amdgcn_mfma_f32_16x16x32_bf16(afrag, bfrag[g], c, 0, 0, 0);
      es0 = fmaf(fmaxf(c[0] + bm1c[g], 0.f), wpcc[g], es0);
      es1 = fmaf(fmaxf(c[1] + bm1c[g], 0.f), wpcc[g], es1);
      es2 = fmaf(fmaxf(c[2] + bm1c[g], 0.f), wpcc[g], es2);
      es3 = fmaf(fmaxf(c[3] + bm1c[g], 0.f), wpcc[g], es3);
    }
#pragma unroll
    for (int m = 1; m < 16; m <<= 1) {
      es0 += __shfl_xor(es0, m);
      es1 += __shfl_xor(es1, m);
      es2 += __shfl_xor(es2, m);
      es3 += __shfl_xor(es3, m);
    }
    if (l15 < 4) {
      float es = (l15 == 0) ? es0 : (l15 == 1) ? es1 : (l15 == 2) ? es2 : es3;
      int e = ebase + kg * 4 + l15;
      int s = ei[e], d = ei[NE + e];
      out[e] = es + u[s] + v[d] + basec;
    }
  }
}

extern "C" void kernel_launch(void* const* d_in, const int* in_sizes, int n_in,
                              void* d_out, int out_size, void* d_ws, size_t ws_size,
                              hipStream_t stream) {
  const float* x   = (const float*)d_in[0];
  const int*   ei  = (const int*)d_in[1];
  const float* ea  = (const float*)d_in[2];
  const float* W1  = (const float*)d_in[3];
  const float* as1 = (const float*)d_in[4];
  const float* ad1 = (const float*)d_in[5];
  const float* b1  = (const float*)d_in[6];
  const float* W2  = (const float*)d_in[7];
  const float* as2 = (const float*)d_in[8];
  const float* ad2 = (const float*)d_in[9];
  const float* b2  = (const float*)d_in[10];
  const float* Wm1 = (const float*)d_in[11];
  const float* bm1 = (const float*)d_in[12];
  const float* Wm2 = (const float*)d_in[13];
  const float* bm2 = (const float*)d_in[14];
  const float* Wf  = (const float*)d_in[15];
  const float* bf  = (const float*)d_in[16];
  float* out = (float*)d_out;

  float* w = (float*)d_ws;
  float* h1   = w; w += (size_t)NN * HP;   // layer1 h; later reused as layer2 agg out
  float* bufB = w; w += (size_t)NN * HP;   // layer1 agg out (h1r) = layer2 gemm input
  float* h2   = w; w += (size_t)NN * HP;
  float* asv  = w; w += NN;
  float* adv  = w; w += NN;
  float* uu   = w; w += NN;
  float* vv   = w; w += NN;
  float* wpc  = w; w += HP;
  float* b1p  = w; w += HP;
  float* b2p  = w; w += HP;
  float* aw   = w; w += ETOT;
  unsigned long long* tmp = (unsigned long long*)w; w += 2 * (size_t)ETOT;  // 8B each
  int* rowptr = (int*)w; w += NN + 1;
  int* srcs   = (int*)w; w += ETOT;
  int* gh     = (int*)w; w += GHN;
  int* goff   = (int*)w; w += GHN;
  int* gsum   = (int*)w; w += GS_NB;
  int* gboff  = (int*)w; w += GS_NB;

  const int B = 256;
  dim3 gN((NN + B - 1) / B);
  dim3 gA((NN * NG + B - 1) / B);
  dim3 gFE((FE_WAVES + 3) / 4);

  // ---- CSR build: blocked counting sort (no global atomics) ----
  bin_hist<<<NBE, B, 0, stream>>>(ei, gh);
  scan1g<<<GS_NB, B, 0, stream>>>(gh, gsum);
  scan2g<<<1, B, 0, stream>>>(gsum, gboff);
  scan3g<<<GS_NB, B, 0, stream>>>(gh, gboff, goff);
  bin_place<<<NBE, B, 0, stream>>>(ei, goff, tmp);
  bucket_build<<<NBUCK, B, 0, stream>>>(tmp, goff, rowptr, srcs);
  prep_bias<<<1, 128, 0, stream>>>(b1, b2, b1p, b2p);

  // ---- layer 1 ----
  gemm_node<FIN, FIN><<<gN, B, 0, stream>>>(x, W1, as1, ad1, h1, asv, adv);
  softmax_csr<<<gN, B, 0, stream>>>(rowptr, srcs, asv, adv, aw);
  agg_csr<1><<<gA, B, 0, stream>>>(rowptr, srcs, aw, h1, b1p, bufB);

  // ---- layer 2 ----
  gemm_node<H, HP><<<gN, B, 0, stream>>>(bufB, W2, as2, ad2, h2, asv, adv);
  softmax_csr<<<gN, B, 0, stream>>>(rowptr, srcs, asv, adv, aw);
  agg_csr<0><<<gA, B, 0, stream>>>(rowptr, srcs, aw, h2, b2p, h1);
  final_node<<<gN, B, 0, stream>>>(h1, Wf, uu, vv);

  // ---- edge head ----
  mk_wproj<<<1, 128, 0, stream>>>(Wm2, bm2, Wf, bf, wpc);
  final_edge_mfma<<<gFE, B, 0, stream>>>(ei, ea, Wm1, bm1, wpc, uu, vv, out);
}

// Round 11
// 386.102 us; speedup vs baseline: 2.5480x; 1.0501x over previous
//
#include <hip/hip_runtime.h>
#include <math.h>

#define NN 50000
#define NE 1200000
#define FIN 128
#define FE 32
#define H 78
#define HP 80
#define ETOT (NE + NN)

#define NPB 64                                   // nodes per bucket
#define NBUCK ((NN + NPB - 1) / NPB)             // 782
#define BCAP 2560                                // max edges/bucket in LDS (mean ~1600)

#define EB 6400                                  // edges per binning block
#define NBE ((ETOT + EB - 1) / EB)               // 196 binning blocks
#define GHN (NBUCK * NBE)                        // 153272 histogram cells
#define GS_NB ((GHN + 1023) / 1024)              // 150 scan tiles

typedef __attribute__((ext_vector_type(8))) short bf16x8;
typedef __attribute__((ext_vector_type(4))) float f32x4;

__device__ __forceinline__ unsigned short f2bf(float f) {   // RNE float->bf16
  unsigned u = __float_as_uint(f);
  return (unsigned short)((u + 0x7FFFu + ((u >> 16) & 1u)) >> 16);
}

// ---------------- dense node GEMM with fused attention-score epilogue ----------------
template<int K, int LDA>
__global__ void gemm_node(const float* __restrict__ A, const float* __restrict__ W,
                          const float* __restrict__ as, const float* __restrict__ ad,
                          float* __restrict__ C, float* __restrict__ asv,
                          float* __restrict__ adv) {
  int n = blockIdx.x * blockDim.x + threadIdx.x;
  if (n >= NN) return;
  const float* a = A + (size_t)n * LDA;
  float acc[H];
#pragma unroll
  for (int j = 0; j < H; ++j) acc[j] = 0.f;
  int k = 0;
  for (; k + 4 <= K; k += 4) {
    float4 av = *reinterpret_cast<const float4*>(a + k);
    const float* w0 = W + (size_t)k * H;
#pragma unroll
    for (int j = 0; j < H; ++j) acc[j] += av.x * w0[j];
#pragma unroll
    for (int j = 0; j < H; ++j) acc[j] += av.y * w0[H + j];
#pragma unroll
    for (int j = 0; j < H; ++j) acc[j] += av.z * w0[2 * H + j];
#pragma unroll
    for (int j = 0; j < H; ++j) acc[j] += av.w * w0[3 * H + j];
  }
  for (; k < K; ++k) {
    float av = a[k];
    const float* w0 = W + (size_t)k * H;
#pragma unroll
    for (int j = 0; j < H; ++j) acc[j] += av * w0[j];
  }
  float* c = C + (size_t)n * HP;
#pragma unroll
  for (int j = 0; j < H; ++j) c[j] = acc[j];
  c[H] = 0.f;
  c[H + 1] = 0.f;
  float sa = 0.f, sd = 0.f;
#pragma unroll
  for (int j = 0; j < H; ++j) {
    sa += acc[j] * as[j];
    sd += acc[j] * ad[j];
  }
  asv[n] = sa;
  adv[n] = sd;
}

// ---------------- CSR build: blocked counting sort, no global atomics --------------
__global__ __launch_bounds__(256)
void bin_hist(const int* __restrict__ ei, int* __restrict__ gh) {
  __shared__ int hist[NBUCK];
  int b = blockIdx.x, t = threadIdx.x;
  for (int k = t; k < NBUCK; k += 256) hist[k] = 0;
  __syncthreads();
  int e0 = b * EB;
  int e1 = min(e0 + EB, ETOT);
  for (int i = e0 + t; i < e1; i += 256) {
    int dst = (i < NE) ? ei[NE + i] : (i - NE);
    atomicAdd(&hist[dst >> 6], 1);
  }
  __syncthreads();
  for (int k = t; k < NBUCK; k += 256) gh[(size_t)k * NBE + b] = hist[k];
}

__global__ void scan1g(const int* __restrict__ gh, int* __restrict__ gsum) {
  __shared__ int sh[256];
  int b = blockIdx.x, t = threadIdx.x;
  int i0 = b * 1024 + t * 4;
  int s = 0;
#pragma unroll
  for (int k = 0; k < 4; ++k) {
    int i = i0 + k;
    if (i < GHN) s += gh[i];
  }
  sh[t] = s;
  __syncthreads();
  for (int off = 128; off > 0; off >>= 1) {
    if (t < off) sh[t] += sh[t + off];
    __syncthreads();
  }
  if (t == 0) gsum[b] = sh[0];
}

__global__ void scan2g(const int* __restrict__ gsum, int* __restrict__ gboff) {
  __shared__ int sh[256];
  int t = threadIdx.x;
  sh[t] = (t < GS_NB) ? gsum[t] : 0;
  __syncthreads();
  for (int off = 1; off < 256; off <<= 1) {
    int v = (t >= off) ? sh[t - off] : 0;
    __syncthreads();
    sh[t] += v;
    __syncthreads();
  }
  if (t < GS_NB) gboff[t] = (t == 0) ? 0 : sh[t - 1];
}

__global__ void scan3g(const int* __restrict__ gh, const int* __restrict__ gboff,
                       int* __restrict__ goff) {
  __shared__ int sh[256];
  int b = blockIdx.x, t = threadIdx.x;
  int i0 = b * 1024 + t * 4;
  int v[4];
  int s = 0;
#pragma unroll
  for (int k = 0; k < 4; ++k) {
    int i = i0 + k;
    v[k] = (i < GHN) ? gh[i] : 0;
    s += v[k];
  }
  sh[t] = s;
  __syncthreads();
  for (int off = 1; off < 256; off <<= 1) {
    int u = (t >= off) ? sh[t - off] : 0;
    __syncthreads();
    sh[t] += u;
    __syncthreads();
  }
  int run = gboff[b] + ((t == 0) ? 0 : sh[t - 1]);
#pragma unroll
  for (int k = 0; k < 4; ++k) {
    int i = i0 + k;
    if (i < GHN) { goff[i] = run; run += v[k]; }
  }
}

__global__ __launch_bounds__(256)
void bin_place(const int* __restrict__ ei, const int* __restrict__ goff,
               unsigned long long* __restrict__ tmp) {
  __shared__ int cursor[NBUCK];
  int b = blockIdx.x, t = threadIdx.x;
  for (int k = t; k < NBUCK; k += 256) cursor[k] = goff[(size_t)k * NBE + b];
  __syncthreads();
  int e0 = b * EB;
  int e1 = min(e0 + EB, ETOT);
  for (int i = e0 + t; i < e1; i += 256) {
    int src, dst;
    if (i < NE) { src = ei[i]; dst = ei[NE + i]; }
    else { src = dst = i - NE; }
    int pos = atomicAdd(&cursor[dst >> 6], 1);
    tmp[pos] = ((unsigned long long)(unsigned)dst << 32) | (unsigned)src;
  }
}

__global__ __launch_bounds__(256)
void bucket_build(const unsigned long long* __restrict__ tmp,
                  const int* __restrict__ goff,
                  int* __restrict__ rowptr, int* __restrict__ srcs) {
  __shared__ int hist[NPB];
  __shared__ int offs[NPB];
  __shared__ int curs[NPB];
  __shared__ int srcs_l[BCAP];
  int b = blockIdx.x, t = threadIdx.x;
  int base = goff[(size_t)b * NBE];
  int next = (b + 1 < NBUCK) ? goff[(size_t)(b + 1) * NBE] : ETOT;
  int cnt = next - base;
  int n0 = b * NPB;
  if (t < NPB) hist[t] = 0;
  __syncthreads();
  for (int p = t; p < cnt; p += 256) {
    int dst = (int)(tmp[base + p] >> 32);
    atomicAdd(&hist[dst - n0], 1);
  }
  __syncthreads();
  if (t == 0) {
    int run = 0;
    for (int j = 0; j < NPB; ++j) { offs[j] = run; run += hist[j]; }
  }
  __syncthreads();
  if (t < NPB) {
    curs[t] = offs[t];
    int n = n0 + t;
    if (n < NN) rowptr[n] = base + offs[t];
  }
  if (b == NBUCK - 1 && t == 0) rowptr[NN] = ETOT;
  __syncthreads();
  for (int p = t; p < cnt; p += 256) {
    unsigned long long e = tmp[base + p];
    int dst = (int)(e >> 32);
    int src = (int)(e & 0xffffffffULL);
    int lp = atomicAdd(&curs[dst - n0], 1);
    if (lp < BCAP) srcs_l[lp] = src;
    else srcs[base + lp] = src;       // overflow fallback (statistically never)
  }
  __syncthreads();
  int m = cnt < BCAP ? cnt : BCAP;
  for (int p = t; p < m; p += 256) srcs[base + p] = srcs_l[p];
}

// ---------------- FUSED per-node softmax + aggregation (wave per node) -------------
// Phase A: lanes gather scores in parallel, butterfly max/sum -> alpha in registers.
// Phase B: per edge, shfl-broadcast (alpha, src); 64 lanes read the 80-float h row
// coalesced and FMA into 2 accumulators/lane. Bias+ReLU epilogue fused.
template<int RELU>
__global__ __launch_bounds__(256)
void gat_fused(const int* __restrict__ rowptr, const int* __restrict__ srcs,
               const float* __restrict__ asv, const float* __restrict__ adv,
               const float* __restrict__ h, const float* __restrict__ bias,
               float* __restrict__ outp) {
  int n = (blockIdx.x * 256 + threadIdx.x) >> 6;   // wave id = node
  int lane = threadIdx.x & 63;
  if (n >= NN) return;
  int r0 = rowptr[n], r1 = rowptr[n + 1];
  int deg = r1 - r0;
  float advn = adv[n];

  // phase A, chunk 0 (deg <= 64 is the hot path)
  int s0 = 0;
  float e0 = -INFINITY;
  if (lane < deg) {
    s0 = srcs[r0 + lane];
    float e = asv[s0] + advn;
    e0 = e > 0.f ? e : 0.2f * e;
  }
  float m = e0;
#pragma unroll
  for (int off = 1; off < 64; off <<= 1) m = fmaxf(m, __shfl_xor(m, off));
  float cs = (lane < deg) ? __expf(e0 - m) : 0.f;
  float ssum = cs;
#pragma unroll
  for (int off = 1; off < 64; off <<= 1) ssum += __shfl_xor(ssum, off);
  // extra chunks (deg > 64; statistically never for this graph, but correct)
  for (int c = r0 + 64; c < r1; c += 64) {
    int p = c + lane;
    float e = -INFINITY;
    if (p < r1) {
      float t = asv[srcs[p]] + advn;
      e = t > 0.f ? t : 0.2f * t;
    }
    float cm = e;
#pragma unroll
    for (int off = 1; off < 64; off <<= 1) cm = fmaxf(cm, __shfl_xor(cm, off));
    float c2 = (p < r1) ? __expf(e - cm) : 0.f;
#pragma unroll
    for (int off = 1; off < 64; off <<= 1) c2 += __shfl_xor(c2, off);
    float mn = fmaxf(m, cm);
    ssum = ssum * __expf(m - mn) + c2 * __expf(cm - mn);
    m = mn;
  }
  float inv = 1.f / (ssum + 1e-16f);

  // phase B
  float acc0 = 0.f, acc1 = 0.f;
  int c1 = lane + 64;                      // cols 64..79 (pads are zero in h)
  float alpha0 = (lane < deg) ? __expf(e0 - m) * inv : 0.f;
  int nch = deg < 64 ? deg : 64;
  for (int p = 0; p < nch; ++p) {
    float al = __shfl(alpha0, p);
    int s = __shfl(s0, p);
    const float* hr = h + (size_t)s * HP;
    acc0 = fmaf(al, hr[lane], acc0);
    if (lane < 16) acc1 = fmaf(al, hr[c1], acc1);
  }
  for (int c = r0 + 64; c < r1; c += 64) {
    int p = c + lane;
    float al = 0.f;
    int s = 0;
    if (p < r1) {
      s = srcs[p];
      float t = asv[s] + advn;
      t = t > 0.f ? t : 0.2f * t;
      al = __expf(t - m) * inv;
    }
    int cnt = min(r1 - c, 64);
    for (int q = 0; q < cnt; ++q) {
      float alq = __shfl(al, q);
      int sq = __shfl(s, q);
      const float* hr = h + (size_t)sq * HP;
      acc0 = fmaf(alq, hr[lane], acc0);
      if (lane < 16) acc1 = fmaf(alq, hr[c1], acc1);
    }
  }

  // epilogue (lane < 64 < H so bias[lane] always valid)
  float* orow = outp + (size_t)n * HP;
  float o0 = acc0 + bias[lane];
  if (RELU) o0 = fmaxf(o0, 0.f);
  orow[lane] = o0;
  if (lane < 16) {
    float bb = (c1 < H) ? bias[c1] : 0.f;
    float o1 = acc1 + bb;
    if (RELU) o1 = fmaxf(o1, 0.f);
    orow[c1] = o1;                        // cols 78,79 stay exactly 0
  }
}

__global__ void final_node(const float* __restrict__ h2f, const float* __restrict__ Wf,
                           float* __restrict__ u, float* __restrict__ v) {
  int n = blockIdx.x * blockDim.x + threadIdx.x;
  if (n >= NN) return;
  const float* r = h2f + (size_t)n * HP;
  float su = 0.f, sv = 0.f;
#pragma unroll
  for (int j = 0; j < H; ++j) {
    float hv = r[j];
    su += hv * Wf[j];
    sv += hv * Wf[H + j];
  }
  u[n] = su;
  v[n] = sv;
}

__global__ void mk_wproj(const float* __restrict__ Wm2, const float* __restrict__ bm2,
                         const float* __restrict__ Wf, const float* __restrict__ bf,
                         float* __restrict__ wpc) {
  int k = threadIdx.x;
  if (k < H) {
    float s = 0.f;
    for (int j = 0; j < H; ++j) s += Wm2[k * H + j] * Wf[2 * H + j];
    wpc[k] = s;
  } else if (k == H) {
    float s = 0.f;
    for (int j = 0; j < H; ++j) s += bm2[j] * Wf[2 * H + j];
    wpc[H] = s + bf[0];
  }
}

// ---------------- edge head via MFMA: ea[E x 32] @ Wm1[32 x 78] -------------
#define FE_WAVES 18750          // NE / 64 edges per wave
__global__ __launch_bounds__(256)
void final_edge_mfma(const int* __restrict__ ei, const float* __restrict__ ea,
                     const float* __restrict__ Wm1, const float* __restrict__ bm1,
                     const float* __restrict__ wpc, const float* __restrict__ u,
                     const float* __restrict__ v, float* __restrict__ out) {
  int lane = threadIdx.x & 63;
  long gw = (long)blockIdx.x * 4 + (threadIdx.x >> 6);
  if (gw >= FE_WAVES) return;
  int l15 = lane & 15;
  int kg = lane >> 4;                    // k-group 0..3
  bf16x8 bfrag[5];
  float bm1c[5], wpcc[5];
#pragma unroll
  for (int g = 0; g < 5; ++g) {
    int col = g * 16 + l15;
    bool valid = col < H;
    bm1c[g] = valid ? bm1[col] : 0.f;
    wpcc[g] = valid ? wpc[col] : 0.f;
#pragma unroll
    for (int e = 0; e < 8; ++e) {
      int kk = kg * 8 + e;
      bfrag[g][e] = valid ? (short)f2bf(Wm1[kk * H + col]) : (short)0;
    }
  }
  float basec = wpc[H];
  int e0 = (int)(gw * 64);
#pragma unroll
  for (int t = 0; t < 4; ++t) {
    int ebase = e0 + t * 16;
    const float* ar = ea + (size_t)(ebase + l15) * FE + kg * 8;
    float4 f0 = *reinterpret_cast<const float4*>(ar);
    float4 f1 = *reinterpret_cast<const float4*>(ar + 4);
    bf16x8 afrag;
    afrag[0] = (short)f2bf(f0.x); afrag[1] = (short)f2bf(f0.y);
    afrag[2] = (short)f2bf(f0.z); afrag[3] = (short)f2bf(f0.w);
    afrag[4] = (short)f2bf(f1.x); afrag[5] = (short)f2bf(f1.y);
    afrag[6] = (short)f2bf(f1.z); afrag[7] = (short)f2bf(f1.w);
    float es0 = 0.f, es1 = 0.f, es2 = 0.f, es3 = 0.f;
#pragma unroll
    for (int g = 0; g < 5; ++g) {
      f32x4 c = {0.f, 0.f, 0.f, 0.f};
      c = __builtin_amdgcn_mfma_f32_16x16x32_bf16(afrag, bfrag[g], c, 0, 0, 0);
      es0 = fmaf(fmaxf(c[0] + bm1c[g], 0.f), wpcc[g], es0);
      es1 = fmaf(fmaxf(c[1] + bm1c[g], 0.f), wpcc[g], es1);
      es2 = fmaf(fmaxf(c[2] + bm1c[g], 0.f), wpcc[g], es2);
      es3 = fmaf(fmaxf(c[3] + bm1c[g], 0.f), wpcc[g], es3);
    }
#pragma unroll
    for (int m = 1; m < 16; m <<= 1) {
      es0 += __shfl_xor(es0, m);
      es1 += __shfl_xor(es1, m);
      es2 += __shfl_xor(es2, m);
      es3 += __shfl_xor(es3, m);
    }
    if (l15 < 4) {
      float es = (l15 == 0) ? es0 : (l15 == 1) ? es1 : (l15 == 2) ? es2 : es3;
      int e = ebase + kg * 4 + l15;
      int s = ei[e], d = ei[NE + e];
      out[e] = es + u[s] + v[d] + basec;
    }
  }
}

extern "C" void kernel_launch(void* const* d_in, const int* in_sizes, int n_in,
                              void* d_out, int out_size, void* d_ws, size_t ws_size,
                              hipStream_t stream) {
  const float* x   = (const float*)d_in[0];
  const int*   ei  = (const int*)d_in[1];
  const float* ea  = (const float*)d_in[2];
  const float* W1  = (const float*)d_in[3];
  const float* as1 = (const float*)d_in[4];
  const float* ad1 = (const float*)d_in[5];
  const float* b1  = (const float*)d_in[6];
  const float* W2  = (const float*)d_in[7];
  const float* as2 = (const float*)d_in[8];
  const float* ad2 = (const float*)d_in[9];
  const float* b2  = (const float*)d_in[10];
  const float* Wm1 = (const float*)d_in[11];
  const float* bm1 = (const float*)d_in[12];
  const float* Wm2 = (const float*)d_in[13];
  const float* bm2 = (const float*)d_in[14];
  const float* Wf  = (const float*)d_in[15];
  const float* bf  = (const float*)d_in[16];
  float* out = (float*)d_out;

  float* w = (float*)d_ws;
  float* h1   = w; w += (size_t)NN * HP;   // layer1 h; later reused as layer2 agg out
  float* bufB = w; w += (size_t)NN * HP;   // layer1 agg out (h1r) = layer2 gemm input
  float* h2   = w; w += (size_t)NN * HP;
  float* asv  = w; w += NN;
  float* adv  = w; w += NN;
  float* uu   = w; w += NN;
  float* vv   = w; w += NN;
  float* wpc  = w; w += HP;
  unsigned long long* tmp = (unsigned long long*)w; w += 2 * (size_t)ETOT;  // 8B each
  int* rowptr = (int*)w; w += NN + 1;
  int* srcs   = (int*)w; w += ETOT;
  int* gh     = (int*)w; w += GHN;
  int* goff   = (int*)w; w += GHN;
  int* gsum   = (int*)w; w += GS_NB;
  int* gboff  = (int*)w; w += GS_NB;

  const int B = 256;
  dim3 gN((NN + B - 1) / B);
  dim3 gW((NN * 64 + B - 1) / B);          // wave per node
  dim3 gFE((FE_WAVES + 3) / 4);

  // ---- CSR build: blocked counting sort (no global atomics) ----
  bin_hist<<<NBE, B, 0, stream>>>(ei, gh);
  scan1g<<<GS_NB, B, 0, stream>>>(gh, gsum);
  scan2g<<<1, B, 0, stream>>>(gsum, gboff);
  scan3g<<<GS_NB, B, 0, stream>>>(gh, gboff, goff);
  bin_place<<<NBE, B, 0, stream>>>(ei, goff, tmp);
  bucket_build<<<NBUCK, B, 0, stream>>>(tmp, goff, rowptr, srcs);

  // ---- layer 1 ----
  gemm_node<FIN, FIN><<<gN, B, 0, stream>>>(x, W1, as1, ad1, h1, asv, adv);
  gat_fused<1><<<gW, B, 0, stream>>>(rowptr, srcs, asv, adv, h1, b1, bufB);

  // ---- layer 2 ----
  gemm_node<H, HP><<<gN, B, 0, stream>>>(bufB, W2, as2, ad2, h2, asv, adv);
  gat_fused<0><<<gW, B, 0, stream>>>(rowptr, srcs, asv, adv, h2, b2, h1);
  final_node<<<gN, B, 0, stream>>>(h1, Wf, uu, vv);

  // ---- edge head ----
  mk_wproj<<<1, 128, 0, stream>>>(Wm2, bm2, Wf, bf, wpc);
  final_edge_mfma<<<gFE, B, 0, stream>>>(ei, ea, Wm1, bm1, wpc, uu, vv, out);
}

// Round 12
// 307.133 us; speedup vs baseline: 3.2031x; 1.2571x over previous
//
#include <hip/hip_runtime.h>
#include <math.h>

#define NN 50000
#define NE 1200000
#define FIN 128
#define FE 32
#define H 78
#define HP 80
#define ETOT (NE + NN)

#define NPB 64                                   // nodes per bucket
#define NBUCK ((NN + NPB - 1) / NPB)             // 782
#define BCAP 2560                                // max edges/bucket in LDS (mean ~1600)

#define EB 6400                                  // edges per binning block
#define NBE ((ETOT + EB - 1) / EB)               // 196 binning blocks
#define GHN (NBUCK * NBE)                        // 153272 histogram cells
#define GS_NB ((GHN + 1023) / 1024)              // 150 scan tiles

typedef __attribute__((ext_vector_type(8))) short bf16x8;
typedef __attribute__((ext_vector_type(4))) float f32x4;

__device__ __forceinline__ unsigned short f2bf(float f) {   // RNE float->bf16
  unsigned u = __float_as_uint(f);
  return (unsigned short)((u + 0x7FFFu + ((u >> 16) & 1u)) >> 16);
}
__device__ __forceinline__ float bf2f(unsigned short b) {
  return __uint_as_float((unsigned)b << 16);
}

// ---------------- dense node GEMM + attention scores + bf16 row copy ----------------
template<int K, int LDA>
__global__ void gemm_node(const float* __restrict__ A, const float* __restrict__ W,
                          const float* __restrict__ as, const float* __restrict__ ad,
                          float* __restrict__ C, unsigned* __restrict__ hb,
                          float* __restrict__ asv, float* __restrict__ adv) {
  int n = blockIdx.x * blockDim.x + threadIdx.x;
  if (n >= NN) return;
  const float* a = A + (size_t)n * LDA;
  float acc[H];
#pragma unroll
  for (int j = 0; j < H; ++j) acc[j] = 0.f;
  int k = 0;
  for (; k + 4 <= K; k += 4) {
    float4 av = *reinterpret_cast<const float4*>(a + k);
    const float* w0 = W + (size_t)k * H;
#pragma unroll
    for (int j = 0; j < H; ++j) acc[j] += av.x * w0[j];
#pragma unroll
    for (int j = 0; j < H; ++j) acc[j] += av.y * w0[H + j];
#pragma unroll
    for (int j = 0; j < H; ++j) acc[j] += av.z * w0[2 * H + j];
#pragma unroll
    for (int j = 0; j < H; ++j) acc[j] += av.w * w0[3 * H + j];
  }
  for (; k < K; ++k) {
    float av = a[k];
    const float* w0 = W + (size_t)k * H;
#pragma unroll
    for (int j = 0; j < H; ++j) acc[j] += av * w0[j];
  }
  float* c = C + (size_t)n * HP;
#pragma unroll
  for (int j = 0; j < H; ++j) c[j] = acc[j];
  c[H] = 0.f;
  c[H + 1] = 0.f;
  unsigned* hbr = hb + (size_t)n * (HP / 2);
#pragma unroll
  for (int j = 0; j < 39; ++j)
    hbr[j] = (unsigned)f2bf(acc[2 * j]) | ((unsigned)f2bf(acc[2 * j + 1]) << 16);
  hbr[39] = 0u;                                  // cols 78,79
  float sa = 0.f, sd = 0.f;
#pragma unroll
  for (int j = 0; j < H; ++j) {
    sa += acc[j] * as[j];
    sd += acc[j] * ad[j];
  }
  asv[n] = sa;
  adv[n] = sd;
}

// ---------------- CSR build: blocked counting sort, no global atomics --------------
__global__ __launch_bounds__(256)
void bin_hist(const int* __restrict__ ei, int* __restrict__ gh) {
  __shared__ int hist[NBUCK];
  int b = blockIdx.x, t = threadIdx.x;
  for (int k = t; k < NBUCK; k += 256) hist[k] = 0;
  __syncthreads();
  int e0 = b * EB;
  int e1 = min(e0 + EB, ETOT);
  for (int i = e0 + t; i < e1; i += 256) {
    int dst = (i < NE) ? ei[NE + i] : (i - NE);
    atomicAdd(&hist[dst >> 6], 1);
  }
  __syncthreads();
  for (int k = t; k < NBUCK; k += 256) gh[(size_t)k * NBE + b] = hist[k];
}

__global__ void scan1g(const int* __restrict__ gh, int* __restrict__ gsum) {
  __shared__ int sh[256];
  int b = blockIdx.x, t = threadIdx.x;
  int i0 = b * 1024 + t * 4;
  int s = 0;
#pragma unroll
  for (int k = 0; k < 4; ++k) {
    int i = i0 + k;
    if (i < GHN) s += gh[i];
  }
  sh[t] = s;
  __syncthreads();
  for (int off = 128; off > 0; off >>= 1) {
    if (t < off) sh[t] += sh[t + off];
    __syncthreads();
  }
  if (t == 0) gsum[b] = sh[0];
}

__global__ void scan2g(const int* __restrict__ gsum, int* __restrict__ gboff) {
  __shared__ int sh[256];
  int t = threadIdx.x;
  sh[t] = (t < GS_NB) ? gsum[t] : 0;
  __syncthreads();
  for (int off = 1; off < 256; off <<= 1) {
    int v = (t >= off) ? sh[t - off] : 0;
    __syncthreads();
    sh[t] += v;
    __syncthreads();
  }
  if (t < GS_NB) gboff[t] = (t == 0) ? 0 : sh[t - 1];
}

__global__ void scan3g(const int* __restrict__ gh, const int* __restrict__ gboff,
                       int* __restrict__ goff) {
  __shared__ int sh[256];
  int b = blockIdx.x, t = threadIdx.x;
  int i0 = b * 1024 + t * 4;
  int v[4];
  int s = 0;
#pragma unroll
  for (int k = 0; k < 4; ++k) {
    int i = i0 + k;
    v[k] = (i < GHN) ? gh[i] : 0;
    s += v[k];
  }
  sh[t] = s;
  __syncthreads();
  for (int off = 1; off < 256; off <<= 1) {
    int u = (t >= off) ? sh[t - off] : 0;
    __syncthreads();
    sh[t] += u;
    __syncthreads();
  }
  int run = gboff[b] + ((t == 0) ? 0 : sh[t - 1]);
#pragma unroll
  for (int k = 0; k < 4; ++k) {
    int i = i0 + k;
    if (i < GHN) { goff[i] = run; run += v[k]; }
  }
}

__global__ __launch_bounds__(256)
void bin_place(const int* __restrict__ ei, const int* __restrict__ goff,
               unsigned long long* __restrict__ tmp) {
  __shared__ int cursor[NBUCK];
  int b = blockIdx.x, t = threadIdx.x;
  for (int k = t; k < NBUCK; k += 256) cursor[k] = goff[(size_t)k * NBE + b];
  __syncthreads();
  int e0 = b * EB;
  int e1 = min(e0 + EB, ETOT);
  for (int i = e0 + t; i < e1; i += 256) {
    int src, dst;
    if (i < NE) { src = ei[i]; dst = ei[NE + i]; }
    else { src = dst = i - NE; }
    int pos = atomicAdd(&cursor[dst >> 6], 1);
    tmp[pos] = ((unsigned long long)(unsigned)dst << 32) | (unsigned)src;
  }
}

__global__ __launch_bounds__(256)
void bucket_build(const unsigned long long* __restrict__ tmp,
                  const int* __restrict__ goff,
                  int* __restrict__ rowptr, int* __restrict__ srcs) {
  __shared__ int hist[NPB];
  __shared__ int offs[NPB];
  __shared__ int curs[NPB];
  __shared__ int srcs_l[BCAP];
  int b = blockIdx.x, t = threadIdx.x;
  int base = goff[(size_t)b * NBE];
  int next = (b + 1 < NBUCK) ? goff[(size_t)(b + 1) * NBE] : ETOT;
  int cnt = next - base;
  int n0 = b * NPB;
  if (t < NPB) hist[t] = 0;
  __syncthreads();
  for (int p = t; p < cnt; p += 256) {
    int dst = (int)(tmp[base + p] >> 32);
    atomicAdd(&hist[dst - n0], 1);
  }
  __syncthreads();
  if (t == 0) {
    int run = 0;
    for (int j = 0; j < NPB; ++j) { offs[j] = run; run += hist[j]; }
  }
  __syncthreads();
  if (t < NPB) {
    curs[t] = offs[t];
    int n = n0 + t;
    if (n < NN) rowptr[n] = base + offs[t];
  }
  if (b == NBUCK - 1 && t == 0) rowptr[NN] = ETOT;
  __syncthreads();
  for (int p = t; p < cnt; p += 256) {
    unsigned long long e = tmp[base + p];
    int dst = (int)(e >> 32);
    int src = (int)(e & 0xffffffffULL);
    int lp = atomicAdd(&curs[dst - n0], 1);
    if (lp < BCAP) srcs_l[lp] = src;
    else srcs[base + lp] = src;       // overflow fallback (statistically never)
  }
  __syncthreads();
  int m = cnt < BCAP ? cnt : BCAP;
  for (int p = t; p < m; p += 256) srcs[base + p] = srcs_l[p];
}

// ---------------- FUSED per-node softmax + aggregation (wave per node) -------------
// Phase A: 64 lanes gather scores, butterfly max/sum -> alpha in registers.
// Phase B: 3 edges/iteration; 20-lane groups read one bf16 row (160B) coalesced,
// fp32 FMA into float4 acc; cross-group shfl reduce; bias+ReLU epilogue.
template<int RELU>
__global__ __launch_bounds__(256)
void gat_fused(const int* __restrict__ rowptr, const int* __restrict__ srcs,
               const float* __restrict__ asv, const float* __restrict__ adv,
               const unsigned* __restrict__ hb, const float* __restrict__ bias,
               float* __restrict__ outp) {
  int n = (blockIdx.x * 256 + threadIdx.x) >> 6;   // wave id = node
  int lane = threadIdx.x & 63;
  if (n >= NN) return;
  int r0 = rowptr[n], r1 = rowptr[n + 1];
  int deg = r1 - r0;
  float advn = adv[n];

  // ---- phase A, chunk 0 (deg <= 64 hot path) ----
  int s0 = 0;
  float e0 = -INFINITY;
  if (lane < deg) {
    s0 = srcs[r0 + lane];
    float e = asv[s0] + advn;
    e0 = e > 0.f ? e : 0.2f * e;
  }
  float m = e0;
#pragma unroll
  for (int off = 1; off < 64; off <<= 1) m = fmaxf(m, __shfl_xor(m, off));
  float ssum = (lane < deg) ? __expf(e0 - m) : 0.f;
#pragma unroll
  for (int off = 1; off < 64; off <<= 1) ssum += __shfl_xor(ssum, off);
  for (int c = r0 + 64; c < r1; c += 64) {      // deg>64: statistically never
    int p = c + lane;
    float e = -INFINITY;
    if (p < r1) {
      float t = asv[srcs[p]] + advn;
      e = t > 0.f ? t : 0.2f * t;
    }
    float cm = e;
#pragma unroll
    for (int off = 1; off < 64; off <<= 1) cm = fmaxf(cm, __shfl_xor(cm, off));
    float c2 = (p < r1) ? __expf(e - cm) : 0.f;
#pragma unroll
    for (int off = 1; off < 64; off <<= 1) c2 += __shfl_xor(c2, off);
    float mn = fmaxf(m, cm);
    ssum = ssum * __expf(m - mn) + c2 * __expf(cm - mn);
    m = mn;
  }
  float inv = 1.f / (ssum + 1e-16f);
  float alpha0 = (lane < deg) ? __expf(e0 - m) * inv : 0.f;

  // ---- phase B: 3 edges / iteration ----
  int g3 = lane / 20;                  // 0..2 active, 3 = idle (lanes 60-63)
  int lp = lane - g3 * 20;             // float4 column group 0..19
  float4 acc = {0.f, 0.f, 0.f, 0.f};
  int nch = deg < 64 ? deg : 64;
  for (int base = 0; base < nch; base += 3) {
    int p = base + g3;
    bool act = (g3 < 3) && (p < nch);
    int idx = p < 63 ? p : 63;
    float al = __shfl(alpha0, idx);
    int s = __shfl(s0, idx);
    if (act) {
      const unsigned* hr = hb + (size_t)s * (HP / 2) + lp * 2;
      unsigned w0 = hr[0], w1 = hr[1];
      acc.x = fmaf(al, bf2f((unsigned short)(w0 & 0xffff)), acc.x);
      acc.y = fmaf(al, bf2f((unsigned short)(w0 >> 16)), acc.y);
      acc.z = fmaf(al, bf2f((unsigned short)(w1 & 0xffff)), acc.z);
      acc.w = fmaf(al, bf2f((unsigned short)(w1 >> 16)), acc.w);
    }
  }
  for (int c = r0 + 64; c < r1; c += 64) {      // overflow chunks (never)
    int p = c + lane;
    float al = 0.f;
    int s = 0;
    if (p < r1) {
      s = srcs[p];
      float t = asv[s] + advn;
      t = t > 0.f ? t : 0.2f * t;
      al = __expf(t - m) * inv;
    }
    int cnt = min(r1 - c, 64);
    for (int base = 0; base < cnt; base += 3) {
      int p2 = base + g3;
      bool act = (g3 < 3) && (p2 < cnt);
      int idx = p2 < 63 ? p2 : 63;
      float alq = __shfl(al, idx);
      int sq = __shfl(s, idx);
      if (act) {
        const unsigned* hr = hb + (size_t)sq * (HP / 2) + lp * 2;
        unsigned w0 = hr[0], w1 = hr[1];
        acc.x = fmaf(alq, bf2f((unsigned short)(w0 & 0xffff)), acc.x);
        acc.y = fmaf(alq, bf2f((unsigned short)(w0 >> 16)), acc.y);
        acc.z = fmaf(alq, bf2f((unsigned short)(w1 & 0xffff)), acc.z);
        acc.w = fmaf(alq, bf2f((unsigned short)(w1 >> 16)), acc.w);
      }
    }
  }

  // ---- cross-group reduce + epilogue ----
  float4 a1, a2;
  a1.x = __shfl(acc.x, lane + 20); a1.y = __shfl(acc.y, lane + 20);
  a1.z = __shfl(acc.z, lane + 20); a1.w = __shfl(acc.w, lane + 20);
  a2.x = __shfl(acc.x, lane + 40); a2.y = __shfl(acc.y, lane + 40);
  a2.z = __shfl(acc.z, lane + 40); a2.w = __shfl(acc.w, lane + 40);
  if (lane < 20) {
    int c0 = lane * 4;
    float4 o;
    o.x = acc.x + a1.x + a2.x + ((c0 + 0 < H) ? bias[c0 + 0] : 0.f);
    o.y = acc.y + a1.y + a2.y + ((c0 + 1 < H) ? bias[c0 + 1] : 0.f);
    o.z = acc.z + a1.z + a2.z + ((c0 + 2 < H) ? bias[c0 + 2] : 0.f);
    o.w = acc.w + a1.w + a2.w + ((c0 + 3 < H) ? bias[c0 + 3] : 0.f);
    if (RELU) {
      o.x = fmaxf(o.x, 0.f); o.y = fmaxf(o.y, 0.f);
      o.z = fmaxf(o.z, 0.f); o.w = fmaxf(o.w, 0.f);
    }
    *reinterpret_cast<float4*>(outp + (size_t)n * HP + c0) = o;
  }
}

__global__ void final_node(const float* __restrict__ h2f, const float* __restrict__ Wf,
                           float* __restrict__ u, float* __restrict__ v) {
  int n = blockIdx.x * blockDim.x + threadIdx.x;
  if (n >= NN) return;
  const float* r = h2f + (size_t)n * HP;
  float su = 0.f, sv = 0.f;
#pragma unroll
  for (int j = 0; j < H; ++j) {
    float hv = r[j];
    su += hv * Wf[j];
    sv += hv * Wf[H + j];
  }
  u[n] = su;
  v[n] = sv;
}

__global__ void mk_wproj(const float* __restrict__ Wm2, const float* __restrict__ bm2,
                         const float* __restrict__ Wf, const float* __restrict__ bf,
                         float* __restrict__ wpc) {
  int k = threadIdx.x;
  if (k < H) {
    float s = 0.f;
    for (int j = 0; j < H; ++j) s += Wm2[k * H + j] * Wf[2 * H + j];
    wpc[k] = s;
  } else if (k == H) {
    float s = 0.f;
    for (int j = 0; j < H; ++j) s += bm2[j] * Wf[2 * H + j];
    wpc[H] = s + bf[0];
  }
}

// ---------------- edge head via MFMA: ea[E x 32] @ Wm1[32 x 78] -------------
#define FE_WAVES 18750          // NE / 64 edges per wave
__global__ __launch_bounds__(256)
void final_edge_mfma(const int* __restrict__ ei, const float* __restrict__ ea,
                     const float* __restrict__ Wm1, const float* __restrict__ bm1,
                     const float* __restrict__ wpc, const float* __restrict__ u,
                     const float* __restrict__ v, float* __restrict__ out) {
  int lane = threadIdx.x & 63;
  long gw = (long)blockIdx.x * 4 + (threadIdx.x >> 6);
  if (gw >= FE_WAVES) return;
  int l15 = lane & 15;
  int kg = lane >> 4;                    // k-group 0..3
  bf16x8 bfrag[5];
  float bm1c[5], wpcc[5];
#pragma unroll
  for (int g = 0; g < 5; ++g) {
    int col = g * 16 + l15;
    bool valid = col < H;
    bm1c[g] = valid ? bm1[col] : 0.f;
    wpcc[g] = valid ? wpc[col] : 0.f;
#pragma unroll
    for (int e = 0; e < 8; ++e) {
      int kk = kg * 8 + e;
      bfrag[g][e] = valid ? (short)f2bf(Wm1[kk * H + col]) : (short)0;
    }
  }
  float basec = wpc[H];
  int e0 = (int)(gw * 64);
#pragma unroll
  for (int t = 0; t < 4; ++t) {
    int ebase = e0 + t * 16;
    const float* ar = ea + (size_t)(ebase + l15) * FE + kg * 8;
    float4 f0 = *reinterpret_cast<const float4*>(ar);
    float4 f1 = *reinterpret_cast<const float4*>(ar + 4);
    bf16x8 afrag;
    afrag[0] = (short)f2bf(f0.x); afrag[1] = (short)f2bf(f0.y);
    afrag[2] = (short)f2bf(f0.z); afrag[3] = (short)f2bf(f0.w);
    afrag[4] = (short)f2bf(f1.x); afrag[5] = (short)f2bf(f1.y);
    afrag[6] = (short)f2bf(f1.z); afrag[7] = (short)f2bf(f1.w);
    float es0 = 0.f, es1 = 0.f, es2 = 0.f, es3 = 0.f;
#pragma unroll
    for (int g = 0; g < 5; ++g) {
      f32x4 c = {0.f, 0.f, 0.f, 0.f};
      c = __builtin_amdgcn_mfma_f32_16x16x32_bf16(afrag, bfrag[g], c, 0, 0, 0);
      es0 = fmaf(fmaxf(c[0] + bm1c[g], 0.f), wpcc[g], es0);
      es1 = fmaf(fmaxf(c[1] + bm1c[g], 0.f), wpcc[g], es1);
      es2 = fmaf(fmaxf(c[2] + bm1c[g], 0.f), wpcc[g], es2);
      es3 = fmaf(fmaxf(c[3] + bm1c[g], 0.f), wpcc[g], es3);
    }
#pragma unroll
    for (int m = 1; m < 16; m <<= 1) {
      es0 += __shfl_xor(es0, m);
      es1 += __shfl_xor(es1, m);
      es2 += __shfl_xor(es2, m);
      es3 += __shfl_xor(es3, m);
    }
    if (l15 < 4) {
      float es = (l15 == 0) ? es0 : (l15 == 1) ? es1 : (l15 == 2) ? es2 : es3;
      int e = ebase + kg * 4 + l15;
      int s = ei[e], d = ei[NE + e];
      out[e] = es + u[s] + v[d] + basec;
    }
  }
}

extern "C" void kernel_launch(void* const* d_in, const int* in_sizes, int n_in,
                              void* d_out, int out_size, void* d_ws, size_t ws_size,
                              hipStream_t stream) {
  const float* x   = (const float*)d_in[0];
  const int*   ei  = (const int*)d_in[1];
  const float* ea  = (const float*)d_in[2];
  const float* W1  = (const float*)d_in[3];
  const float* as1 = (const float*)d_in[4];
  const float* ad1 = (const float*)d_in[5];
  const float* b1  = (const float*)d_in[6];
  const float* W2  = (const float*)d_in[7];
  const float* as2 = (const float*)d_in[8];
  const float* ad2 = (const float*)d_in[9];
  const float* b2  = (const float*)d_in[10];
  const float* Wm1 = (const float*)d_in[11];
  const float* bm1 = (const float*)d_in[12];
  const float* Wm2 = (const float*)d_in[13];
  const float* bm2 = (const float*)d_in[14];
  const float* Wf  = (const float*)d_in[15];
  const float* bf  = (const float*)d_in[16];
  float* out = (float*)d_out;

  float* w = (float*)d_ws;
  float* h1   = w; w += (size_t)NN * HP;   // layer1 h fp32; reused as layer2 agg out
  float* bufB = w; w += (size_t)NN * HP;   // layer1 agg out = layer2 gemm input
  float* h2   = w; w += (size_t)NN * HP;
  unsigned* hb = (unsigned*)w; w += (size_t)NN * (HP / 2);  // bf16 h copy (packed)
  float* asv  = w; w += NN;
  float* adv  = w; w += NN;
  float* uu   = w; w += NN;
  float* vv   = w; w += NN;
  float* wpc  = w; w += HP;
  unsigned long long* tmp = (unsigned long long*)w; w += 2 * (size_t)ETOT;  // 8B each
  int* rowptr = (int*)w; w += NN + 1;
  int* srcs   = (int*)w; w += ETOT;
  int* gh     = (int*)w; w += GHN;
  int* goff   = (int*)w; w += GHN;
  int* gsum   = (int*)w; w += GS_NB;
  int* gboff  = (int*)w; w += GS_NB;

  const int B = 256;
  dim3 gN((NN + B - 1) / B);
  dim3 gW((NN * 64 + B - 1) / B);          // wave per node
  dim3 gFE((FE_WAVES + 3) / 4);

  // ---- CSR build: blocked counting sort (no global atomics) ----
  bin_hist<<<NBE, B, 0, stream>>>(ei, gh);
  scan1g<<<GS_NB, B, 0, stream>>>(gh, gsum);
  scan2g<<<1, B, 0, stream>>>(gsum, gboff);
  scan3g<<<GS_NB, B, 0, stream>>>(gh, gboff, goff);
  bin_place<<<NBE, B, 0, stream>>>(ei, goff, tmp);
  bucket_build<<<NBUCK, B, 0, stream>>>(tmp, goff, rowptr, srcs);

  // ---- layer 1 ----
  gemm_node<FIN, FIN><<<gN, B, 0, stream>>>(x, W1, as1, ad1, h1, hb, asv, adv);
  gat_fused<1><<<gW, B, 0, stream>>>(rowptr, srcs, asv, adv, hb, b1, bufB);

  // ---- layer 2 ----
  gemm_node<H, HP><<<gN, B, 0, stream>>>(bufB, W2, as2, ad2, h2, hb, asv, adv);
  gat_fused<0><<<gW, B, 0, stream>>>(rowptr, srcs, asv, adv, hb, b2, h1);
  final_node<<<gN, B, 0, stream>>>(h1, Wf, uu, vv);

  // ---- edge head ----
  mk_wproj<<<1, 128, 0, stream>>>(Wm2, bm2, Wf, bf, wpc);
  final_edge_mfma<<<gFE, B, 0, stream>>>(ei, ea, Wm1, bm1, wpc, uu, vv, out);
}

// Round 13
// 231.261 us; speedup vs baseline: 4.2539x; 1.3281x over previous
//
#include <hip/hip_runtime.h>
#include <math.h>

#define NN 50000
#define NE 1200000
#define FIN 128
#define FE 32
#define H 78
#define HP 80
#define ETOT (NE + NN)

#define NPB 64                                   // nodes per bucket
#define NBUCK ((NN + NPB - 1) / NPB)             // 782
#define BCAP 2560                                // max edges/bucket in LDS (mean ~1600)

#define EB 6400                                  // edges per binning block
#define NBE ((ETOT + EB - 1) / EB)               // 196 binning blocks
#define GHN (NBUCK * NBE)                        // 153272 histogram cells
#define GS_NB ((GHN + 1023) / 1024)              // 150 scan tiles

typedef __attribute__((ext_vector_type(8))) short bf16x8;
typedef __attribute__((ext_vector_type(4))) float f32x4;

__device__ __forceinline__ unsigned short f2bf(float f) {   // RNE float->bf16
  unsigned u = __float_as_uint(f);
  return (unsigned short)((u + 0x7FFFu + ((u >> 16) & 1u)) >> 16);
}
__device__ __forceinline__ float bf2f(unsigned short b) {
  return __uint_as_float((unsigned)b << 16);
}

union Frag { uint4 q; bf16x8 v; unsigned short u[8]; };

// ---------------- W permute: frag-ordered bf16 split (Wh, Wl) ----------------
// fid = (step*5+g)*2+split; lane holds W[step*32+(lane>>4)*8+e][16g+(lane&15)], e=0..7
__global__ void wperm_build(const float* __restrict__ W, int K, int steps,
                            uint4* __restrict__ out) {
  int idx = blockIdx.x * blockDim.x + threadIdx.x;
  int total = steps * 5 * 2 * 64;
  if (idx >= total) return;
  int lane = idx & 63;
  int fid = idx >> 6;
  int split = fid & 1;
  int sg = fid >> 1;
  int step = sg / 5, g = sg % 5;
  int kg = lane >> 4, l15 = lane & 15;
  int col = g * 16 + l15;
  Frag f;
#pragma unroll
  for (int e = 0; e < 8; ++e) {
    int k = step * 32 + kg * 8 + e;
    float v = (k < K && col < H) ? W[(size_t)k * H + col] : 0.f;
    unsigned short h = f2bf(v);
    if (split) h = f2bf(v - bf2f(h));
    f.u[e] = h;
  }
  out[idx] = f.q;
}

// ---------------- MFMA node GEMM: split-bf16 (~fp32 accuracy) ----------------
// Wave = 16 nodes. Outputs: packed-bf16 h rows (hb) + attention scores asv/adv.
template<int STEPS, int LDA>
__global__ __launch_bounds__(256)
void gemm_mfma(const float* __restrict__ A, const uint4* __restrict__ wperm,
               const float* __restrict__ as, const float* __restrict__ ad,
               unsigned* __restrict__ hb, float* __restrict__ asv,
               float* __restrict__ adv) {
  int lane = threadIdx.x & 63;
  int gw = blockIdx.x * 4 + (threadIdx.x >> 6);
  int n0w = gw * 16;
  if (n0w >= NN) return;
  int l15 = lane & 15, kg = lane >> 4;
  f32x4 acc[5];
#pragma unroll
  for (int g = 0; g < 5; ++g) acc[g] = (f32x4){0.f, 0.f, 0.f, 0.f};

#pragma unroll
  for (int step = 0; step < STEPS; ++step) {
    int k0 = step * 32 + kg * 8;
    bf16x8 ah, al;
    if (k0 < LDA) {
      int row = n0w + l15;
      if (row >= NN) row = NN - 1;
      const float* ar = A + (size_t)row * LDA + k0;
      float4 f0 = *reinterpret_cast<const float4*>(ar);
      float4 f1 = *reinterpret_cast<const float4*>(ar + 4);
      float fv[8] = {f0.x, f0.y, f0.z, f0.w, f1.x, f1.y, f1.z, f1.w};
#pragma unroll
      for (int e = 0; e < 8; ++e) {
        unsigned short h = f2bf(fv[e]);
        ah[e] = (short)h;
        al[e] = (short)f2bf(fv[e] - bf2f(h));
      }
    } else {
#pragma unroll
      for (int e = 0; e < 8; ++e) { ah[e] = 0; al[e] = 0; }
    }
#pragma unroll
    for (int g = 0; g < 5; ++g) {
      Frag wh, wl;
      wh.q = wperm[((size_t)(step * 5 + g) * 2 + 0) * 64 + lane];
      wl.q = wperm[((size_t)(step * 5 + g) * 2 + 1) * 64 + lane];
      acc[g] = __builtin_amdgcn_mfma_f32_16x16x32_bf16(ah, wh.v, acc[g], 0, 0, 0);
      acc[g] = __builtin_amdgcn_mfma_f32_16x16x32_bf16(al, wh.v, acc[g], 0, 0, 0);
      acc[g] = __builtin_amdgcn_mfma_f32_16x16x32_bf16(ah, wl.v, acc[g], 0, 0, 0);
    }
  }

  // per-lane score weights (col = g*16+l15)
  float asl[5], adl[5];
#pragma unroll
  for (int g = 0; g < 5; ++g) {
    int col = g * 16 + l15;
    asl[g] = (col < H) ? as[col] : 0.f;
    adl[g] = (col < H) ? ad[col] : 0.f;
  }

#pragma unroll
  for (int r = 0; r < 4; ++r) {
    int node = n0w + kg * 4 + r;
    // hb pack: even l15 lanes pack (col, col+1)
#pragma unroll
    for (int g = 0; g < 5; ++g) {
      float c = acc[g][r];
      float cn = __shfl_xor(c, 1);
      if (!(l15 & 1) && node < NN)
        hb[(size_t)node * (HP / 2) + g * 8 + (l15 >> 1)] =
            (unsigned)f2bf(c) | ((unsigned)f2bf(cn) << 16);
    }
    // attention score dots: reduce over the 16-lane col group
    float sa = 0.f, sd = 0.f;
#pragma unroll
    for (int g = 0; g < 5; ++g) {
      sa = fmaf(acc[g][r], asl[g], sa);
      sd = fmaf(acc[g][r], adl[g], sd);
    }
#pragma unroll
    for (int mask = 1; mask < 16; mask <<= 1) {
      sa += __shfl_xor(sa, mask);
      sd += __shfl_xor(sd, mask);
    }
    if (l15 == 0 && node < NN) { asv[node] = sa; adv[node] = sd; }
  }
}

// ---------------- CSR build: blocked counting sort, no global atomics --------------
__global__ __launch_bounds__(256)
void bin_hist(const int* __restrict__ ei, int* __restrict__ gh) {
  __shared__ int hist[NBUCK];
  int b = blockIdx.x, t = threadIdx.x;
  for (int k = t; k < NBUCK; k += 256) hist[k] = 0;
  __syncthreads();
  int e0 = b * EB;
  int e1 = min(e0 + EB, ETOT);
  for (int i = e0 + t; i < e1; i += 256) {
    int dst = (i < NE) ? ei[NE + i] : (i - NE);
    atomicAdd(&hist[dst >> 6], 1);
  }
  __syncthreads();
  for (int k = t; k < NBUCK; k += 256) gh[(size_t)k * NBE + b] = hist[k];
}

__global__ void scan1g(const int* __restrict__ gh, int* __restrict__ gsum) {
  __shared__ int sh[256];
  int b = blockIdx.x, t = threadIdx.x;
  int i0 = b * 1024 + t * 4;
  int s = 0;
#pragma unroll
  for (int k = 0; k < 4; ++k) {
    int i = i0 + k;
    if (i < GHN) s += gh[i];
  }
  sh[t] = s;
  __syncthreads();
  for (int off = 128; off > 0; off >>= 1) {
    if (t < off) sh[t] += sh[t + off];
    __syncthreads();
  }
  if (t == 0) gsum[b] = sh[0];
}

__global__ void scan2g(const int* __restrict__ gsum, int* __restrict__ gboff) {
  __shared__ int sh[256];
  int t = threadIdx.x;
  sh[t] = (t < GS_NB) ? gsum[t] : 0;
  __syncthreads();
  for (int off = 1; off < 256; off <<= 1) {
    int v = (t >= off) ? sh[t - off] : 0;
    __syncthreads();
    sh[t] += v;
    __syncthreads();
  }
  if (t < GS_NB) gboff[t] = (t == 0) ? 0 : sh[t - 1];
}

__global__ void scan3g(const int* __restrict__ gh, const int* __restrict__ gboff,
                       int* __restrict__ goff) {
  __shared__ int sh[256];
  int b = blockIdx.x, t = threadIdx.x;
  int i0 = b * 1024 + t * 4;
  int v[4];
  int s = 0;
#pragma unroll
  for (int k = 0; k < 4; ++k) {
    int i = i0 + k;
    v[k] = (i < GHN) ? gh[i] : 0;
    s += v[k];
  }
  sh[t] = s;
  __syncthreads();
  for (int off = 1; off < 256; off <<= 1) {
    int u = (t >= off) ? sh[t - off] : 0;
    __syncthreads();
    sh[t] += u;
    __syncthreads();
  }
  int run = gboff[b] + ((t == 0) ? 0 : sh[t - 1]);
#pragma unroll
  for (int k = 0; k < 4; ++k) {
    int i = i0 + k;
    if (i < GHN) { goff[i] = run; run += v[k]; }
  }
}

__global__ __launch_bounds__(256)
void bin_place(const int* __restrict__ ei, const int* __restrict__ goff,
               unsigned long long* __restrict__ tmp) {
  __shared__ int cursor[NBUCK];
  int b = blockIdx.x, t = threadIdx.x;
  for (int k = t; k < NBUCK; k += 256) cursor[k] = goff[(size_t)k * NBE + b];
  __syncthreads();
  int e0 = b * EB;
  int e1 = min(e0 + EB, ETOT);
  for (int i = e0 + t; i < e1; i += 256) {
    int src, dst;
    if (i < NE) { src = ei[i]; dst = ei[NE + i]; }
    else { src = dst = i - NE; }
    int pos = atomicAdd(&cursor[dst >> 6], 1);
    tmp[pos] = ((unsigned long long)(unsigned)dst << 32) | (unsigned)src;
  }
}

__global__ __launch_bounds__(256)
void bucket_build(const unsigned long long* __restrict__ tmp,
                  const int* __restrict__ goff,
                  int* __restrict__ rowptr, int* __restrict__ srcs) {
  __shared__ int hist[NPB];
  __shared__ int offs[NPB];
  __shared__ int curs[NPB];
  __shared__ int srcs_l[BCAP];
  int b = blockIdx.x, t = threadIdx.x;
  int base = goff[(size_t)b * NBE];
  int next = (b + 1 < NBUCK) ? goff[(size_t)(b + 1) * NBE] : ETOT;
  int cnt = next - base;
  int n0 = b * NPB;
  if (t < NPB) hist[t] = 0;
  __syncthreads();
  for (int p = t; p < cnt; p += 256) {
    int dst = (int)(tmp[base + p] >> 32);
    atomicAdd(&hist[dst - n0], 1);
  }
  __syncthreads();
  if (t == 0) {
    int run = 0;
    for (int j = 0; j < NPB; ++j) { offs[j] = run; run += hist[j]; }
  }
  __syncthreads();
  if (t < NPB) {
    curs[t] = offs[t];
    int n = n0 + t;
    if (n < NN) rowptr[n] = base + offs[t];
  }
  if (b == NBUCK - 1 && t == 0) rowptr[NN] = ETOT;
  __syncthreads();
  for (int p = t; p < cnt; p += 256) {
    unsigned long long e = tmp[base + p];
    int dst = (int)(e >> 32);
    int src = (int)(e & 0xffffffffULL);
    int lp = atomicAdd(&curs[dst - n0], 1);
    if (lp < BCAP) srcs_l[lp] = src;
    else srcs[base + lp] = src;       // overflow fallback (statistically never)
  }
  __syncthreads();
  int m = cnt < BCAP ? cnt : BCAP;
  for (int p = t; p < m; p += 256) srcs[base + p] = srcs_l[p];
}

// ---------------- FUSED per-node softmax + aggregation (wave per node) -------------
template<int RELU>
__global__ __launch_bounds__(256)
void gat_fused(const int* __restrict__ rowptr, const int* __restrict__ srcs,
               const float* __restrict__ asv, const float* __restrict__ adv,
               const unsigned* __restrict__ hb, const float* __restrict__ bias,
               float* __restrict__ outp) {
  int n = (blockIdx.x * 256 + threadIdx.x) >> 6;   // wave id = node
  int lane = threadIdx.x & 63;
  if (n >= NN) return;
  int r0 = rowptr[n], r1 = rowptr[n + 1];
  int deg = r1 - r0;
  float advn = adv[n];

  // ---- phase A, chunk 0 (deg <= 64 hot path) ----
  int s0 = 0;
  float e0 = -INFINITY;
  if (lane < deg) {
    s0 = srcs[r0 + lane];
    float e = asv[s0] + advn;
    e0 = e > 0.f ? e : 0.2f * e;
  }
  float m = e0;
#pragma unroll
  for (int off = 1; off < 64; off <<= 1) m = fmaxf(m, __shfl_xor(m, off));
  float ssum = (lane < deg) ? __expf(e0 - m) : 0.f;
#pragma unroll
  for (int off = 1; off < 64; off <<= 1) ssum += __shfl_xor(ssum, off);
  for (int c = r0 + 64; c < r1; c += 64) {      // deg>64: statistically never
    int p = c + lane;
    float e = -INFINITY;
    if (p < r1) {
      float t = asv[srcs[p]] + advn;
      e = t > 0.f ? t : 0.2f * t;
    }
    float cm = e;
#pragma unroll
    for (int off = 1; off < 64; off <<= 1) cm = fmaxf(cm, __shfl_xor(cm, off));
    float c2 = (p < r1) ? __expf(e - cm) : 0.f;
#pragma unroll
    for (int off = 1; off < 64; off <<= 1) c2 += __shfl_xor(c2, off);
    float mn = fmaxf(m, cm);
    ssum = ssum * __expf(m - mn) + c2 * __expf(cm - mn);
    m = mn;
  }
  float inv = 1.f / (ssum + 1e-16f);
  float alpha0 = (lane < deg) ? __expf(e0 - m) * inv : 0.f;

  // ---- phase B: 3 edges / iteration ----
  int g3 = lane / 20;                  // 0..2 active, 3 = idle (lanes 60-63)
  int lp = lane - g3 * 20;             // float4 column group 0..19
  float4 acc = {0.f, 0.f, 0.f, 0.f};
  int nch = deg < 64 ? deg : 64;
  for (int base = 0; base < nch; base += 3) {
    int p = base + g3;
    bool act = (g3 < 3) && (p < nch);
    int idx = p < 63 ? p : 63;
    float al = __shfl(alpha0, idx);
    int s = __shfl(s0, idx);
    if (act) {
      const unsigned* hr = hb + (size_t)s * (HP / 2) + lp * 2;
      unsigned w0 = hr[0], w1 = hr[1];
      acc.x = fmaf(al, bf2f((unsigned short)(w0 & 0xffff)), acc.x);
      acc.y = fmaf(al, bf2f((unsigned short)(w0 >> 16)), acc.y);
      acc.z = fmaf(al, bf2f((unsigned short)(w1 & 0xffff)), acc.z);
      acc.w = fmaf(al, bf2f((unsigned short)(w1 >> 16)), acc.w);
    }
  }
  for (int c = r0 + 64; c < r1; c += 64) {      // overflow chunks (never)
    int p = c + lane;
    float al = 0.f;
    int s = 0;
    if (p < r1) {
      s = srcs[p];
      float t = asv[s] + advn;
      t = t > 0.f ? t : 0.2f * t;
      al = __expf(t - m) * inv;
    }
    int cnt = min(r1 - c, 64);
    for (int base = 0; base < cnt; base += 3) {
      int p2 = base + g3;
      bool act = (g3 < 3) && (p2 < cnt);
      int idx = p2 < 63 ? p2 : 63;
      float alq = __shfl(al, idx);
      int sq = __shfl(s, idx);
      if (act) {
        const unsigned* hr = hb + (size_t)sq * (HP / 2) + lp * 2;
        unsigned w0 = hr[0], w1 = hr[1];
        acc.x = fmaf(alq, bf2f((unsigned short)(w0 & 0xffff)), acc.x);
        acc.y = fmaf(alq, bf2f((unsigned short)(w0 >> 16)), acc.y);
        acc.z = fmaf(alq, bf2f((unsigned short)(w1 & 0xffff)), acc.z);
        acc.w = fmaf(alq, bf2f((unsigned short)(w1 >> 16)), acc.w);
      }
    }
  }

  // ---- cross-group reduce + epilogue ----
  float4 a1, a2;
  a1.x = __shfl(acc.x, lane + 20); a1.y = __shfl(acc.y, lane + 20);
  a1.z = __shfl(acc.z, lane + 20); a1.w = __shfl(acc.w, lane + 20);
  a2.x = __shfl(acc.x, lane + 40); a2.y = __shfl(acc.y, lane + 40);
  a2.z = __shfl(acc.z, lane + 40); a2.w = __shfl(acc.w, lane + 40);
  if (lane < 20) {
    int c0 = lane * 4;
    float4 o;
    o.x = acc.x + a1.x + a2.x + ((c0 + 0 < H) ? bias[c0 + 0] : 0.f);
    o.y = acc.y + a1.y + a2.y + ((c0 + 1 < H) ? bias[c0 + 1] : 0.f);
    o.z = acc.z + a1.z + a2.z + ((c0 + 2 < H) ? bias[c0 + 2] : 0.f);
    o.w = acc.w + a1.w + a2.w + ((c0 + 3 < H) ? bias[c0 + 3] : 0.f);
    if (RELU) {
      o.x = fmaxf(o.x, 0.f); o.y = fmaxf(o.y, 0.f);
      o.z = fmaxf(o.z, 0.f); o.w = fmaxf(o.w, 0.f);
    }
    *reinterpret_cast<float4*>(outp + (size_t)n * HP + c0) = o;
  }
}

__global__ void final_node(const float* __restrict__ h2f, const float* __restrict__ Wf,
                           float* __restrict__ u, float* __restrict__ v) {
  int n = blockIdx.x * blockDim.x + threadIdx.x;
  if (n >= NN) return;
  const float* r = h2f + (size_t)n * HP;
  float su = 0.f, sv = 0.f;
#pragma unroll
  for (int j = 0; j < H; ++j) {
    float hv = r[j];
    su += hv * Wf[j];
    sv += hv * Wf[H + j];
  }
  u[n] = su;
  v[n] = sv;
}

__global__ void mk_wproj(const float* __restrict__ Wm2, const float* __restrict__ bm2,
                         const float* __restrict__ Wf, const float* __restrict__ bf,
                         float* __restrict__ wpc) {
  int k = threadIdx.x;
  if (k < H) {
    float s = 0.f;
    for (int j = 0; j < H; ++j) s += Wm2[k * H + j] * Wf[2 * H + j];
    wpc[k] = s;
  } else if (k == H) {
    float s = 0.f;
    for (int j = 0; j < H; ++j) s += bm2[j] * Wf[2 * H + j];
    wpc[H] = s + bf[0];
  }
}

// ---------------- edge head via MFMA: ea[E x 32] @ Wm1[32 x 78] -------------
#define FE_WAVES 18750          // NE / 64 edges per wave
__global__ __launch_bounds__(256)
void final_edge_mfma(const int* __restrict__ ei, const float* __restrict__ ea,
                     const float* __restrict__ Wm1, const float* __restrict__ bm1,
                     const float* __restrict__ wpc, const float* __restrict__ u,
                     const float* __restrict__ v, float* __restrict__ out) {
  int lane = threadIdx.x & 63;
  long gw = (long)blockIdx.x * 4 + (threadIdx.x >> 6);
  if (gw >= FE_WAVES) return;
  int l15 = lane & 15;
  int kg = lane >> 4;                    // k-group 0..3
  bf16x8 bfrag[5];
  float bm1c[5], wpcc[5];
#pragma unroll
  for (int g = 0; g < 5; ++g) {
    int col = g * 16 + l15;
    bool valid = col < H;
    bm1c[g] = valid ? bm1[col] : 0.f;
    wpcc[g] = valid ? wpc[col] : 0.f;
#pragma unroll
    for (int e = 0; e < 8; ++e) {
      int kk = kg * 8 + e;
      bfrag[g][e] = valid ? (short)f2bf(Wm1[kk * H + col]) : (short)0;
    }
  }
  float basec = wpc[H];
  int e0 = (int)(gw * 64);
#pragma unroll
  for (int t = 0; t < 4; ++t) {
    int ebase = e0 + t * 16;
    const float* ar = ea + (size_t)(ebase + l15) * FE + kg * 8;
    float4 f0 = *reinterpret_cast<const float4*>(ar);
    float4 f1 = *reinterpret_cast<const float4*>(ar + 4);
    bf16x8 afrag;
    afrag[0] = (short)f2bf(f0.x); afrag[1] = (short)f2bf(f0.y);
    afrag[2] = (short)f2bf(f0.z); afrag[3] = (short)f2bf(f0.w);
    afrag[4] = (short)f2bf(f1.x); afrag[5] = (short)f2bf(f1.y);
    afrag[6] = (short)f2bf(f1.z); afrag[7] = (short)f2bf(f1.w);
    float es0 = 0.f, es1 = 0.f, es2 = 0.f, es3 = 0.f;
#pragma unroll
    for (int g = 0; g < 5; ++g) {
      f32x4 c = {0.f, 0.f, 0.f, 0.f};
      c = __builtin_amdgcn_mfma_f32_16x16x32_bf16(afrag, bfrag[g], c, 0, 0, 0);
      es0 = fmaf(fmaxf(c[0] + bm1c[g], 0.f), wpcc[g], es0);
      es1 = fmaf(fmaxf(c[1] + bm1c[g], 0.f), wpcc[g], es1);
      es2 = fmaf(fmaxf(c[2] + bm1c[g], 0.f), wpcc[g], es2);
      es3 = fmaf(fmaxf(c[3] + bm1c[g], 0.f), wpcc[g], es3);
    }
#pragma unroll
    for (int m = 1; m < 16; m <<= 1) {
      es0 += __shfl_xor(es0, m);
      es1 += __shfl_xor(es1, m);
      es2 += __shfl_xor(es2, m);
      es3 += __shfl_xor(es3, m);
    }
    if (l15 < 4) {
      float es = (l15 == 0) ? es0 : (l15 == 1) ? es1 : (l15 == 2) ? es2 : es3;
      int e = ebase + kg * 4 + l15;
      int s = ei[e], d = ei[NE + e];
      out[e] = es + u[s] + v[d] + basec;
    }
  }
}

extern "C" void kernel_launch(void* const* d_in, const int* in_sizes, int n_in,
                              void* d_out, int out_size, void* d_ws, size_t ws_size,
                              hipStream_t stream) {
  const float* x   = (const float*)d_in[0];
  const int*   ei  = (const int*)d_in[1];
  const float* ea  = (const float*)d_in[2];
  const float* W1  = (const float*)d_in[3];
  const float* as1 = (const float*)d_in[4];
  const float* ad1 = (const float*)d_in[5];
  const float* b1  = (const float*)d_in[6];
  const float* W2  = (const float*)d_in[7];
  const float* as2 = (const float*)d_in[8];
  const float* ad2 = (const float*)d_in[9];
  const float* b2  = (const float*)d_in[10];
  const float* Wm1 = (const float*)d_in[11];
  const float* bm1 = (const float*)d_in[12];
  const float* Wm2 = (const float*)d_in[13];
  const float* bm2 = (const float*)d_in[14];
  const float* Wf  = (const float*)d_in[15];
  const float* bf  = (const float*)d_in[16];
  float* out = (float*)d_out;

  float* w = (float*)d_ws;
  float* h1   = w; w += (size_t)NN * HP;   // layer2 agg out (read by final_node)
  float* bufB = w; w += (size_t)NN * HP;   // layer1 agg out = layer2 gemm input
  unsigned* hb = (unsigned*)w; w += (size_t)NN * (HP / 2);  // bf16 h copy (packed)
  uint4* wperm1 = (uint4*)w; w += 4 * 40 * 64;   // 40 frags x 64 lanes x 16B
  uint4* wperm2 = (uint4*)w; w += 4 * 30 * 64;   // 30 frags
  float* asv  = w; w += NN;
  float* adv  = w; w += NN;
  float* uu   = w; w += NN;
  float* vv   = w; w += NN;
  float* wpc  = w; w += HP;
  unsigned long long* tmp = (unsigned long long*)w; w += 2 * (size_t)ETOT;  // 8B each
  int* rowptr = (int*)w; w += NN + 1;
  int* srcs   = (int*)w; w += ETOT;
  int* gh     = (int*)w; w += GHN;
  int* goff   = (int*)w; w += GHN;
  int* gsum   = (int*)w; w += GS_NB;
  int* gboff  = (int*)w; w += GS_NB;

  const int B = 256;
  dim3 gN((NN + B - 1) / B);
  dim3 gG((NN + 63) / 64);                 // gemm_mfma: 64 nodes / block
  dim3 gW((NN * 64 + B - 1) / B);          // gat_fused: wave per node
  dim3 gFE((FE_WAVES + 3) / 4);

  // ---- W permutes for MFMA gemms ----
  wperm_build<<<(40 * 64 + B - 1) / B, B, 0, stream>>>(W1, FIN, 4, wperm1);
  wperm_build<<<(30 * 64 + B - 1) / B, B, 0, stream>>>(W2, H, 3, wperm2);

  // ---- CSR build: blocked counting sort (no global atomics) ----
  bin_hist<<<NBE, B, 0, stream>>>(ei, gh);
  scan1g<<<GS_NB, B, 0, stream>>>(gh, gsum);
  scan2g<<<1, B, 0, stream>>>(gsum, gboff);
  scan3g<<<GS_NB, B, 0, stream>>>(gh, gboff, goff);
  bin_place<<<NBE, B, 0, stream>>>(ei, goff, tmp);
  bucket_build<<<NBUCK, B, 0, stream>>>(tmp, goff, rowptr, srcs);

  // ---- layer 1 ----
  gemm_mfma<4, FIN><<<gG, B, 0, stream>>>(x, wperm1, as1, ad1, hb, asv, adv);
  gat_fused<1><<<gW, B, 0, stream>>>(rowptr, srcs, asv, adv, hb, b1, bufB);

  // ---- layer 2 ----
  gemm_mfma<3, HP><<<gG, B, 0, stream>>>(bufB, wperm2, as2, ad2, hb, asv, adv);
  gat_fused<0><<<gW, B, 0, stream>>>(rowptr, srcs, asv, adv, hb, b2, h1);
  final_node<<<gN, B, 0, stream>>>(h1, Wf, uu, vv);

  // ---- edge head ----
  mk_wproj<<<1, 128, 0, stream>>>(Wm2, bm2, Wf, bf, wpc);
  final_edge_mfma<<<gFE, B, 0, stream>>>(ei, ea, Wm1, bm1, wpc, uu, vv, out);
}

// Round 14
// 216.778 us; speedup vs baseline: 4.5381x; 1.0668x over previous
//
#include <hip/hip_runtime.h>
#include <math.h>

#define NN 50000
#define NE 1200000
#define FIN 128
#define FE 32
#define H 78
#define HP 80
#define ETOT (NE + NN)

#define NPB 64                                   // nodes per bucket
#define NBUCK ((NN + NPB - 1) / NPB)             // 782
#define BCAP 2560                                // max edges/bucket in LDS (mean ~1600)

#define EB 3200                                  // edges per binning block
#define NBE ((ETOT + EB - 1) / EB)               // 391 binning blocks
#define GHN (NBUCK * NBE)                        // 305,762 histogram cells
#define GS_NB ((GHN + 1023) / 1024)              // 299 scan tiles

typedef __attribute__((ext_vector_type(8))) short bf16x8;
typedef __attribute__((ext_vector_type(4))) float f32x4;

__device__ __forceinline__ unsigned short f2bf(float f) {   // RNE float->bf16
  unsigned u = __float_as_uint(f);
  return (unsigned short)((u + 0x7FFFu + ((u >> 16) & 1u)) >> 16);
}
__device__ __forceinline__ float bf2f(unsigned short b) {
  return __uint_as_float((unsigned)b << 16);
}

union Frag { uint4 q; bf16x8 v; unsigned short u[8]; };

// ---------------- prep: W permutes (split bf16, frag order) + wpc ----------------
__device__ __forceinline__ void wperm_one(const float* __restrict__ W, int K, int idx,
                                          uint4* __restrict__ out) {
  int lane = idx & 63;
  int fid = idx >> 6;
  int split = fid & 1;
  int sg = fid >> 1;
  int step = sg / 5, g = sg % 5;
  int kg = lane >> 4, l15 = lane & 15;
  int col = g * 16 + l15;
  Frag f;
#pragma unroll
  for (int e = 0; e < 8; ++e) {
    int k = step * 32 + kg * 8 + e;
    float v = (k < K && col < H) ? W[(size_t)k * H + col] : 0.f;
    unsigned short h = f2bf(v);
    if (split) h = f2bf(v - bf2f(h));
    f.u[e] = h;
  }
  out[idx] = f.q;
}

__global__ void prep_all(const float* __restrict__ W1, const float* __restrict__ W2,
                         const float* __restrict__ Wm2, const float* __restrict__ bm2,
                         const float* __restrict__ Wf, const float* __restrict__ bf,
                         uint4* __restrict__ wperm1, uint4* __restrict__ wperm2,
                         float* __restrict__ wpc) {
  int b = blockIdx.x, t = threadIdx.x;
  if (b < 10) {
    wperm_one(W1, FIN, b * 256 + t, wperm1);          // 40 frags = 2560 threads
  } else if (b < 18) {
    int idx = (b - 10) * 256 + t;
    if (idx < 30 * 64) wperm_one(W2, H, idx, wperm2); // 30 frags
  } else {
    int k = t;
    if (k < H) {
      float s = 0.f;
      for (int j = 0; j < H; ++j) s += Wm2[k * H + j] * Wf[2 * H + j];
      wpc[k] = s;
    } else if (k == H) {
      float s = 0.f;
      for (int j = 0; j < H; ++j) s += bm2[j] * Wf[2 * H + j];
      wpc[H] = s + bf[0];
    }
  }
}

// ---------------- MFMA node GEMM: split-bf16 (~fp32 accuracy) ----------------
template<int STEPS, int LDA>
__global__ __launch_bounds__(256)
void gemm_mfma(const float* __restrict__ A, const uint4* __restrict__ wperm,
               const float* __restrict__ as, const float* __restrict__ ad,
               unsigned* __restrict__ hb, float* __restrict__ asv,
               float* __restrict__ adv) {
  int lane = threadIdx.x & 63;
  int gw = blockIdx.x * 4 + (threadIdx.x >> 6);
  int n0w = gw * 16;
  if (n0w >= NN) return;
  int l15 = lane & 15, kg = lane >> 4;
  f32x4 acc[5];
#pragma unroll
  for (int g = 0; g < 5; ++g) acc[g] = (f32x4){0.f, 0.f, 0.f, 0.f};

#pragma unroll
  for (int step = 0; step < STEPS; ++step) {
    int k0 = step * 32 + kg * 8;
    bf16x8 ah, al;
    if (k0 < LDA) {
      int row = n0w + l15;
      if (row >= NN) row = NN - 1;
      const float* ar = A + (size_t)row * LDA + k0;
      float4 f0 = *reinterpret_cast<const float4*>(ar);
      float4 f1 = *reinterpret_cast<const float4*>(ar + 4);
      float fv[8] = {f0.x, f0.y, f0.z, f0.w, f1.x, f1.y, f1.z, f1.w};
#pragma unroll
      for (int e = 0; e < 8; ++e) {
        unsigned short h = f2bf(fv[e]);
        ah[e] = (short)h;
        al[e] = (short)f2bf(fv[e] - bf2f(h));
      }
    } else {
#pragma unroll
      for (int e = 0; e < 8; ++e) { ah[e] = 0; al[e] = 0; }
    }
#pragma unroll
    for (int g = 0; g < 5; ++g) {
      Frag wh, wl;
      wh.q = wperm[((size_t)(step * 5 + g) * 2 + 0) * 64 + lane];
      wl.q = wperm[((size_t)(step * 5 + g) * 2 + 1) * 64 + lane];
      acc[g] = __builtin_amdgcn_mfma_f32_16x16x32_bf16(ah, wh.v, acc[g], 0, 0, 0);
      acc[g] = __builtin_amdgcn_mfma_f32_16x16x32_bf16(al, wh.v, acc[g], 0, 0, 0);
      acc[g] = __builtin_amdgcn_mfma_f32_16x16x32_bf16(ah, wl.v, acc[g], 0, 0, 0);
    }
  }

  float asl[5], adl[5];
#pragma unroll
  for (int g = 0; g < 5; ++g) {
    int col = g * 16 + l15;
    asl[g] = (col < H) ? as[col] : 0.f;
    adl[g] = (col < H) ? ad[col] : 0.f;
  }

#pragma unroll
  for (int r = 0; r < 4; ++r) {
    int node = n0w + kg * 4 + r;
#pragma unroll
    for (int g = 0; g < 5; ++g) {
      float c = acc[g][r];
      float cn = __shfl_xor(c, 1);
      if (!(l15 & 1) && node < NN)
        hb[(size_t)node * (HP / 2) + g * 8 + (l15 >> 1)] =
            (unsigned)f2bf(c) | ((unsigned)f2bf(cn) << 16);
    }
    float sa = 0.f, sd = 0.f;
#pragma unroll
    for (int g = 0; g < 5; ++g) {
      sa = fmaf(acc[g][r], asl[g], sa);
      sd = fmaf(acc[g][r], adl[g], sd);
    }
#pragma unroll
    for (int mask = 1; mask < 16; mask <<= 1) {
      sa += __shfl_xor(sa, mask);
      sd += __shfl_xor(sd, mask);
    }
    if (l15 == 0 && node < NN) { asv[node] = sa; adv[node] = sd; }
  }
}

// ---------------- CSR build: blocked counting sort, no global atomics --------------
__global__ __launch_bounds__(256)
void bin_hist(const int* __restrict__ ei, int* __restrict__ gh) {
  __shared__ int hist[NBUCK];
  int b = blockIdx.x, t = threadIdx.x;
  for (int k = t; k < NBUCK; k += 256) hist[k] = 0;
  __syncthreads();
  int e0 = b * EB;
  int e1 = min(e0 + EB, ETOT);
  for (int i = e0 + t; i < e1; i += 256) {
    int dst = (i < NE) ? ei[NE + i] : (i - NE);
    atomicAdd(&hist[dst >> 6], 1);
  }
  __syncthreads();
  for (int k = t; k < NBUCK; k += 256) gh[(size_t)k * NBE + b] = hist[k];
}

__global__ void scan1g(const int* __restrict__ gh, int* __restrict__ gsum) {
  __shared__ int sh[256];
  int b = blockIdx.x, t = threadIdx.x;
  int i0 = b * 1024 + t * 4;
  int s = 0;
#pragma unroll
  for (int k = 0; k < 4; ++k) {
    int i = i0 + k;
    if (i < GHN) s += gh[i];
  }
  sh[t] = s;
  __syncthreads();
  for (int off = 128; off > 0; off >>= 1) {
    if (t < off) sh[t] += sh[t + off];
    __syncthreads();
  }
  if (t == 0) gsum[b] = sh[0];
}

__global__ void scan2g(const int* __restrict__ gsum, int* __restrict__ gboff) {
  __shared__ int sh[512];
  int t = threadIdx.x;
  sh[t] = (t < GS_NB) ? gsum[t] : 0;
  __syncthreads();
  for (int off = 1; off < 512; off <<= 1) {
    int v = (t >= off) ? sh[t - off] : 0;
    __syncthreads();
    sh[t] += v;
    __syncthreads();
  }
  if (t < GS_NB) gboff[t] = (t == 0) ? 0 : sh[t - 1];
}

__global__ void scan3g(const int* __restrict__ gh, const int* __restrict__ gboff,
                       int* __restrict__ goff) {
  __shared__ int sh[256];
  int b = blockIdx.x, t = threadIdx.x;
  int i0 = b * 1024 + t * 4;
  int v[4];
  int s = 0;
#pragma unroll
  for (int k = 0; k < 4; ++k) {
    int i = i0 + k;
    v[k] = (i < GHN) ? gh[i] : 0;
    s += v[k];
  }
  sh[t] = s;
  __syncthreads();
  for (int off = 1; off < 256; off <<= 1) {
    int u = (t >= off) ? sh[t - off] : 0;
    __syncthreads();
    sh[t] += u;
    __syncthreads();
  }
  int run = gboff[b] + ((t == 0) ? 0 : sh[t - 1]);
#pragma unroll
  for (int k = 0; k < 4; ++k) {
    int i = i0 + k;
    if (i < GHN) { goff[i] = run; run += v[k]; }
  }
}

__global__ __launch_bounds__(256)
void bin_place(const int* __restrict__ ei, const int* __restrict__ goff,
               unsigned long long* __restrict__ tmp) {
  __shared__ int cursor[NBUCK];
  int b = blockIdx.x, t = threadIdx.x;
  for (int k = t; k < NBUCK; k += 256) cursor[k] = goff[(size_t)k * NBE + b];
  __syncthreads();
  int e0 = b * EB;
  int e1 = min(e0 + EB, ETOT);
  for (int i = e0 + t; i < e1; i += 256) {
    int src, dst;
    if (i < NE) { src = ei[i]; dst = ei[NE + i]; }
    else { src = dst = i - NE; }
    int pos = atomicAdd(&cursor[dst >> 6], 1);
    tmp[pos] = ((unsigned long long)(unsigned)dst << 32) | (unsigned)src;
  }
}

__global__ __launch_bounds__(256)
void bucket_build(const unsigned long long* __restrict__ tmp,
                  const int* __restrict__ goff,
                  int* __restrict__ rowptr, int* __restrict__ srcs) {
  __shared__ int hist[NPB];
  __shared__ int offs[NPB];
  __shared__ int curs[NPB];
  __shared__ int srcs_l[BCAP];
  int b = blockIdx.x, t = threadIdx.x;
  int base = goff[(size_t)b * NBE];
  int next = (b + 1 < NBUCK) ? goff[(size_t)(b + 1) * NBE] : ETOT;
  int cnt = next - base;
  int n0 = b * NPB;
  if (t < NPB) hist[t] = 0;
  __syncthreads();
  for (int p = t; p < cnt; p += 256) {
    int dst = (int)(tmp[base + p] >> 32);
    atomicAdd(&hist[dst - n0], 1);
  }
  __syncthreads();
  if (t == 0) {
    int run = 0;
    for (int j = 0; j < NPB; ++j) { offs[j] = run; run += hist[j]; }
  }
  __syncthreads();
  if (t < NPB) {
    curs[t] = offs[t];
    int n = n0 + t;
    if (n < NN) rowptr[n] = base + offs[t];
  }
  if (b == NBUCK - 1 && t == 0) rowptr[NN] = ETOT;
  __syncthreads();
  for (int p = t; p < cnt; p += 256) {
    unsigned long long e = tmp[base + p];
    int dst = (int)(e >> 32);
    int src = (int)(e & 0xffffffffULL);
    int lp = atomicAdd(&curs[dst - n0], 1);
    if (lp < BCAP) srcs_l[lp] = src;
    else srcs[base + lp] = src;       // overflow fallback (statistically never)
  }
  __syncthreads();
  int m = cnt < BCAP ? cnt : BCAP;
  for (int p = t; p < m; p += 256) srcs[base + p] = srcs_l[p];
}

// ---------------- FUSED softmax + aggregation (+final u,v dots when FINAL) --------
template<int RELU, int FINAL>
__global__ __launch_bounds__(256)
void gat_fused(const int* __restrict__ rowptr, const int* __restrict__ srcs,
               const float* __restrict__ asv, const float* __restrict__ adv,
               const unsigned* __restrict__ hb, const float* __restrict__ bias,
               const float* __restrict__ Wf, float* __restrict__ outp,
               float* __restrict__ uu, float* __restrict__ vv) {
  int n = (blockIdx.x * 256 + threadIdx.x) >> 6;   // wave id = node
  int lane = threadIdx.x & 63;
  if (n >= NN) return;
  int r0 = rowptr[n], r1 = rowptr[n + 1];
  int deg = r1 - r0;
  float advn = adv[n];

  // ---- phase A (deg <= 64 hot path) ----
  int s0 = 0;
  float e0 = -INFINITY;
  if (lane < deg) {
    s0 = srcs[r0 + lane];
    float e = asv[s0] + advn;
    e0 = e > 0.f ? e : 0.2f * e;
  }
  float m = e0;
#pragma unroll
  for (int off = 1; off < 64; off <<= 1) m = fmaxf(m, __shfl_xor(m, off));
  float ssum = (lane < deg) ? __expf(e0 - m) : 0.f;
#pragma unroll
  for (int off = 1; off < 64; off <<= 1) ssum += __shfl_xor(ssum, off);
  for (int c = r0 + 64; c < r1; c += 64) {      // deg>64: statistically never
    int p = c + lane;
    float e = -INFINITY;
    if (p < r1) {
      float t = asv[srcs[p]] + advn;
      e = t > 0.f ? t : 0.2f * t;
    }
    float cm = e;
#pragma unroll
    for (int off = 1; off < 64; off <<= 1) cm = fmaxf(cm, __shfl_xor(cm, off));
    float c2 = (p < r1) ? __expf(e - cm) : 0.f;
#pragma unroll
    for (int off = 1; off < 64; off <<= 1) c2 += __shfl_xor(c2, off);
    float mn = fmaxf(m, cm);
    ssum = ssum * __expf(m - mn) + c2 * __expf(cm - mn);
    m = mn;
  }
  float inv = 1.f / (ssum + 1e-16f);
  float alpha0 = (lane < deg) ? __expf(e0 - m) * inv : 0.f;

  // ---- phase B: 3 edges / iteration ----
  int g3 = lane / 20;                  // 0..2 active, 3 = idle (lanes 60-63)
  int lp = lane - g3 * 20;             // float4 column group 0..19
  float4 acc = {0.f, 0.f, 0.f, 0.f};
  int nch = deg < 64 ? deg : 64;
  for (int base = 0; base < nch; base += 3) {
    int p = base + g3;
    bool act = (g3 < 3) && (p < nch);
    int idx = p < 63 ? p : 63;
    float al = __shfl(alpha0, idx);
    int s = __shfl(s0, idx);
    if (act) {
      uint2 w01 = *reinterpret_cast<const uint2*>(hb + (size_t)s * (HP / 2) + lp * 2);
      acc.x = fmaf(al, bf2f((unsigned short)(w01.x & 0xffff)), acc.x);
      acc.y = fmaf(al, bf2f((unsigned short)(w01.x >> 16)), acc.y);
      acc.z = fmaf(al, bf2f((unsigned short)(w01.y & 0xffff)), acc.z);
      acc.w = fmaf(al, bf2f((unsigned short)(w01.y >> 16)), acc.w);
    }
  }
  for (int c = r0 + 64; c < r1; c += 64) {      // overflow chunks (never)
    int p = c + lane;
    float al = 0.f;
    int s = 0;
    if (p < r1) {
      s = srcs[p];
      float t = asv[s] + advn;
      t = t > 0.f ? t : 0.2f * t;
      al = __expf(t - m) * inv;
    }
    int cnt = min(r1 - c, 64);
    for (int base = 0; base < cnt; base += 3) {
      int p2 = base + g3;
      bool act = (g3 < 3) && (p2 < cnt);
      int idx = p2 < 63 ? p2 : 63;
      float alq = __shfl(al, idx);
      int sq = __shfl(s, idx);
      if (act) {
        uint2 w01 = *reinterpret_cast<const uint2*>(hb + (size_t)sq * (HP / 2) + lp * 2);
        acc.x = fmaf(alq, bf2f((unsigned short)(w01.x & 0xffff)), acc.x);
        acc.y = fmaf(alq, bf2f((unsigned short)(w01.x >> 16)), acc.y);
        acc.z = fmaf(alq, bf2f((unsigned short)(w01.y & 0xffff)), acc.z);
        acc.w = fmaf(alq, bf2f((unsigned short)(w01.y >> 16)), acc.w);
      }
    }
  }

  // ---- cross-group reduce ----
  float4 a1, a2;
  a1.x = __shfl(acc.x, lane + 20); a1.y = __shfl(acc.y, lane + 20);
  a1.z = __shfl(acc.z, lane + 20); a1.w = __shfl(acc.w, lane + 20);
  a2.x = __shfl(acc.x, lane + 40); a2.y = __shfl(acc.y, lane + 40);
  a2.z = __shfl(acc.z, lane + 40); a2.w = __shfl(acc.w, lane + 40);

  if (FINAL) {
    // fused final_node: u = row . Wf[0:H], v = row . Wf[H:2H]; b2 folded here
    float su = 0.f, sv = 0.f;
    if (lane < 20) {
      int c0 = lane * 4;
      float o0 = acc.x + a1.x + a2.x + ((c0 + 0 < H) ? bias[c0 + 0] : 0.f);
      float o1 = acc.y + a1.y + a2.y + ((c0 + 1 < H) ? bias[c0 + 1] : 0.f);
      float o2 = acc.z + a1.z + a2.z + ((c0 + 2 < H) ? bias[c0 + 2] : 0.f);
      float o3 = acc.w + a1.w + a2.w + ((c0 + 3 < H) ? bias[c0 + 3] : 0.f);
      float wu0 = (c0 + 0 < H) ? Wf[c0 + 0] : 0.f;
      float wu1 = (c0 + 1 < H) ? Wf[c0 + 1] : 0.f;
      float wu2 = (c0 + 2 < H) ? Wf[c0 + 2] : 0.f;
      float wu3 = (c0 + 3 < H) ? Wf[c0 + 3] : 0.f;
      float wv0 = (c0 + 0 < H) ? Wf[H + c0 + 0] : 0.f;
      float wv1 = (c0 + 1 < H) ? Wf[H + c0 + 1] : 0.f;
      float wv2 = (c0 + 2 < H) ? Wf[H + c0 + 2] : 0.f;
      float wv3 = (c0 + 3 < H) ? Wf[H + c0 + 3] : 0.f;
      su = o0 * wu0 + o1 * wu1 + o2 * wu2 + o3 * wu3;
      sv = o0 * wv0 + o1 * wv1 + o2 * wv2 + o3 * wv3;
    }
#pragma unroll
    for (int off = 1; off < 64; off <<= 1) {
      su += __shfl_xor(su, off);
      sv += __shfl_xor(sv, off);
    }
    if (lane == 0) { uu[n] = su; vv[n] = sv; }
  } else {
    if (lane < 20) {
      int c0 = lane * 4;
      float4 o;
      o.x = acc.x + a1.x + a2.x + ((c0 + 0 < H) ? bias[c0 + 0] : 0.f);
      o.y = acc.y + a1.y + a2.y + ((c0 + 1 < H) ? bias[c0 + 1] : 0.f);
      o.z = acc.z + a1.z + a2.z + ((c0 + 2 < H) ? bias[c0 + 2] : 0.f);
      o.w = acc.w + a1.w + a2.w + ((c0 + 3 < H) ? bias[c0 + 3] : 0.f);
      if (RELU) {
        o.x = fmaxf(o.x, 0.f); o.y = fmaxf(o.y, 0.f);
        o.z = fmaxf(o.z, 0.f); o.w = fmaxf(o.w, 0.f);
      }
      *reinterpret_cast<float4*>(outp + (size_t)n * HP + c0) = o;
    }
  }
}

// ---------------- edge head via MFMA: ea[E x 32] @ Wm1[32 x 78] -------------
#define FE_WAVES 18750          // NE / 64 edges per wave
__global__ __launch_bounds__(256)
void final_edge_mfma(const int* __restrict__ ei, const float* __restrict__ ea,
                     const float* __restrict__ Wm1, const float* __restrict__ bm1,
                     const float* __restrict__ wpc, const float* __restrict__ u,
                     const float* __restrict__ v, float* __restrict__ out) {
  int lane = threadIdx.x & 63;
  long gw = (long)blockIdx.x * 4 + (threadIdx.x >> 6);
  if (gw >= FE_WAVES) return;
  int l15 = lane & 15;
  int kg = lane >> 4;                    // k-group 0..3
  bf16x8 bfrag[5];
  float bm1c[5], wpcc[5];
#pragma unroll
  for (int g = 0; g < 5; ++g) {
    int col = g * 16 + l15;
    bool valid = col < H;
    bm1c[g] = valid ? bm1[col] : 0.f;
    wpcc[g] = valid ? wpc[col] : 0.f;
#pragma unroll
    for (int e = 0; e < 8; ++e) {
      int kk = kg * 8 + e;
      bfrag[g][e] = valid ? (short)f2bf(Wm1[kk * H + col]) : (short)0;
    }
  }
  float basec = wpc[H];
  int e0 = (int)(gw * 64);
#pragma unroll
  for (int t = 0; t < 4; ++t) {
    int ebase = e0 + t * 16;
    const float* ar = ea + (size_t)(ebase + l15) * FE + kg * 8;
    float4 f0 = *reinterpret_cast<const float4*>(ar);
    float4 f1 = *reinterpret_cast<const float4*>(ar + 4);
    bf16x8 afrag;
    afrag[0] = (short)f2bf(f0.x); afrag[1] = (short)f2bf(f0.y);
    afrag[2] = (short)f2bf(f0.z); afrag[3] = (short)f2bf(f0.w);
    afrag[4] = (short)f2bf(f1.x); afrag[5] = (short)f2bf(f1.y);
    afrag[6] = (short)f2bf(f1.z); afrag[7] = (short)f2bf(f1.w);
    float es0 = 0.f, es1 = 0.f, es2 = 0.f, es3 = 0.f;
#pragma unroll
    for (int g = 0; g < 5; ++g) {
      f32x4 c = {0.f, 0.f, 0.f, 0.f};
      c = __builtin_amdgcn_mfma_f32_16x16x32_bf16(afrag, bfrag[g], c, 0, 0, 0);
      es0 = fmaf(fmaxf(c[0] + bm1c[g], 0.f), wpcc[g], es0);
      es1 = fmaf(fmaxf(c[1] + bm1c[g], 0.f), wpcc[g], es1);
      es2 = fmaf(fmaxf(c[2] + bm1c[g], 0.f), wpcc[g], es2);
      es3 = fmaf(fmaxf(c[3] + bm1c[g], 0.f), wpcc[g], es3);
    }
#pragma unroll
    for (int m = 1; m < 16; m <<= 1) {
      es0 += __shfl_xor(es0, m);
      es1 += __shfl_xor(es1, m);
      es2 += __shfl_xor(es2, m);
      es3 += __shfl_xor(es3, m);
    }
    if (l15 < 4) {
      float es = (l15 == 0) ? es0 : (l15 == 1) ? es1 : (l15 == 2) ? es2 : es3;
      int e = ebase + kg * 4 + l15;
      int s = ei[e], d = ei[NE + e];
      out[e] = es + u[s] + v[d] + basec;
    }
  }
}

extern "C" void kernel_launch(void* const* d_in, const int* in_sizes, int n_in,
                              void* d_out, int out_size, void* d_ws, size_t ws_size,
                              hipStream_t stream) {
  const float* x   = (const float*)d_in[0];
  const int*   ei  = (const int*)d_in[1];
  const float* ea  = (const float*)d_in[2];
  const float* W1  = (const float*)d_in[3];
  const float* as1 = (const float*)d_in[4];
  const float* ad1 = (const float*)d_in[5];
  const float* b1  = (const float*)d_in[6];
  const float* W2  = (const float*)d_in[7];
  const float* as2 = (const float*)d_in[8];
  const float* ad2 = (const float*)d_in[9];
  const float* b2  = (const float*)d_in[10];
  const float* Wm1 = (const float*)d_in[11];
  const float* bm1 = (const float*)d_in[12];
  const float* Wm2 = (const float*)d_in[13];
  const float* bm2 = (const float*)d_in[14];
  const float* Wf  = (const float*)d_in[15];
  const float* bf  = (const float*)d_in[16];
  float* out = (float*)d_out;

  float* w = (float*)d_ws;
  float* bufB = w; w += (size_t)NN * HP;   // layer1 agg out = layer2 gemm input
  unsigned* hb = (unsigned*)w; w += (size_t)NN * (HP / 2);  // bf16 h copy (packed)
  uint4* wperm1 = (uint4*)w; w += 4 * 40 * 64;   // 40 frags x 64 lanes x 16B
  uint4* wperm2 = (uint4*)w; w += 4 * 30 * 64;   // 30 frags
  float* asv  = w; w += NN;
  float* adv  = w; w += NN;
  float* uu   = w; w += NN;
  float* vv   = w; w += NN;
  float* wpc  = w; w += HP;
  unsigned long long* tmp = (unsigned long long*)w; w += 2 * (size_t)ETOT;  // 8B each
  int* rowptr = (int*)w; w += NN + 1;
  int* srcs   = (int*)w; w += ETOT;
  int* gh     = (int*)w; w += GHN;
  int* goff   = (int*)w; w += GHN;
  int* gsum   = (int*)w; w += GS_NB;
  int* gboff  = (int*)w; w += GS_NB;

  const int B = 256;
  dim3 gG((NN + 63) / 64);                 // gemm_mfma: 64 nodes / block
  dim3 gW((NN * 64 + B - 1) / B);          // gat_fused: wave per node
  dim3 gFE((FE_WAVES + 3) / 4);

  // ---- prep (W permutes + wpc) ----
  prep_all<<<19, B, 0, stream>>>(W1, W2, Wm2, bm2, Wf, bf, wperm1, wperm2, wpc);

  // ---- CSR build: blocked counting sort (no global atomics) ----
  bin_hist<<<NBE, B, 0, stream>>>(ei, gh);
  scan1g<<<GS_NB, B, 0, stream>>>(gh, gsum);
  scan2g<<<1, 512, 0, stream>>>(gsum, gboff);
  scan3g<<<GS_NB, B, 0, stream>>>(gh, gboff, goff);
  bin_place<<<NBE, B, 0, stream>>>(ei, goff, tmp);
  bucket_build<<<NBUCK, B, 0, stream>>>(tmp, goff, rowptr, srcs);

  // ---- layer 1 ----
  gemm_mfma<4, FIN><<<gG, B, 0, stream>>>(x, wperm1, as1, ad1, hb, asv, adv);
  gat_fused<1, 0><<<gW, B, 0, stream>>>(rowptr, srcs, asv, adv, hb, b1, Wf,
                                        bufB, uu, vv);

  // ---- layer 2 (u,v fused into epilogue; no row write) ----
  gemm_mfma<3, HP><<<gG, B, 0, stream>>>(bufB, wperm2, as2, ad2, hb, asv, adv);
  gat_fused<0, 1><<<gW, B, 0, stream>>>(rowptr, srcs, asv, adv, hb, b2, Wf,
                                        nullptr, uu, vv);

  // ---- edge head ----
  final_edge_mfma<<<gFE, B, 0, stream>>>(ei, ea, Wm1, bm1, wpc, uu, vv, out);
}